// Round 9
// baseline (643.769 us; speedup 1.0000x reference)
//
#include <hip/hip_runtime.h>
#include <math.h>

#define SD_  (512*512)
#define BSD_ (16*512*512)

typedef unsigned short u16;
typedef short s16x8 __attribute__((ext_vector_type(8)));
typedef float f32x4 __attribute__((ext_vector_type(4)));

__device__ __forceinline__ float sigmoidf_(float x) { return 1.0f / (1.0f + __expf(-x)); }

__device__ __forceinline__ u16 f2bf(float f) {
    unsigned int u = __float_as_uint(f);
    u += 0x7fffu + ((u >> 16) & 1u);
    return (u16)(u >> 16);
}
__device__ __forceinline__ float bf2f(u16 h) { return __uint_as_float((unsigned)h << 16); }

__device__ __forceinline__ void glds16(const void* g, void* l) {
    __builtin_amdgcn_global_load_lds((const __attribute__((address_space(1))) unsigned int*)g,
                                     (__attribute__((address_space(3))) unsigned int*)l, 16, 0, 0);
}

// ---------------------------------------------------------------------------
// bf16 MFMA GEMM v13 (resubmit; R8 bench was an infra failure, source audited
// clean: slot algebra, vmcnt counting, barrier uniformity, swizzle bijection,
// buffer bounds all verified). Tile 128x64, BK=64 (8 iters @ K=512), 512 thr
// = 8 waves (wave 32x32, 2x2 mfma 16x16x32, kh-unroll 2 -> 8 mfma/iter).
// 2 LDS buffers x 24 KB = 48 KB -> 3 blocks/CU (R7 analysis: nothing
// saturated at 2 blocks/CU; staging 5 B/cyc/CU vs m97's 23 at 3 blocks/CU ->
// residency is the last untested axis; grids double -> 1024/512 blocks).
// Counted-vmcnt schedule (R5): stage(k+1)=3 glds; vmcnt(3) certifies own
// stage(k) while stage(k+1) stays in flight; barrier; compute; barrier.
// Coalesced epilogue (R7) adapted: Ci/CT via LDS [64][136], C via [128][72].
// A row-major [M][K] (128 rows), B N-major [N][K] (64 rows), frag-major LDS.
// ASEL: DG bf16 -> per-thread A source POINTER select only.
// EPI: 0=store 1=+bias 3=+Cin 4=PReLU((acc+bS*bias+Cin)*invden) 6=sigm(+bias)
//      7=+bias+Cin 8=gate: sigm(acc+Cin)*sc[row]*Aeff(row,col)
// ---------------------------------------------------------------------------
struct GP {
    const u16 *A1, *A2;  int lda1, lda2;  long sA;
    const u16 *B1, *B2;  int ldb1, ldb2;  long sB;
    void *C1, *C2;  int obf1, obf2, ldc1, ldc2;  long sC;   // obf: 0=fp32 direct, 1=bf16 LDS-coalesced
    u16 *CT1, *CT2;  long sCT;                              // transposed [b][d][s] (ld=512, batch SD_)
    const void *Ci1, *Ci2;  int cm1, cm2, ldci1, ldci2;  long sCi1, sCi2;  // cm: 0=fp32 normal, 1=bf16 transposed
    const float *bias;  float bS;
    const float *sc1, *sc2;
    const int *selm1, *seli1, *selm2, *seli2;
    const u16 *DG;                                          // bf16 [B*8][512]
    const float *invden, *prelu;  int pidx;
    int M, K, zs, swzX, swzY;
};

template<int EPI, int ASEL>
__global__ __launch_bounds__(512, 6)
void gemm3(const GP p)
{
    __shared__ short LS[24576];   // 48 KB: 2 bufs x (A 8192 + B 4096 shorts)
    const int tid = threadIdx.x;
    int bx, by, bz;
    if (p.swzX >= 0) {
        const int bid = blockIdx.x + gridDim.x * (blockIdx.y + gridDim.y * blockIdx.z);
        const int ppx = (gridDim.y * gridDim.z) >> 3;
        const int xcd = bid & 7, idx = bid >> 3;
        const int pair = xcd * ppx + (idx >> p.swzX);
        bx = idx & ((1 << p.swzX) - 1);
        by = pair & ((1 << p.swzY) - 1);
        bz = pair >> p.swzY;
    } else { bx = blockIdx.x; by = blockIdx.y; bz = blockIdx.z; }

    const int seg = (bz >= p.zs) ? 1 : 0;
    const int z = seg ? bz - p.zs : bz;
    const u16* Ab = (seg ? p.A2 : p.A1) + z * p.sA;
    const int lda = seg ? p.lda2 : p.lda1;
    const u16* Bb = (seg ? p.B2 : p.B1) + z * p.sB;
    const int ldb = seg ? p.ldb2 : p.ldb1;

    const int m0 = by * 128, n0 = bx * 64;
    const int srow = ((tid >> 6) << 4) | (tid & 15);              // 0..127 (A rows)
    const int sk0 = ((tid >> 4) & 3) << 3;                        // 0,8,16,24
    const int slot = ((srow >> 4) << 9) + (sk0 << 4) + ((srow & 15) << 3);
    const int srB = (((tid >> 6) & 3) << 4) | (tid & 15);         // 0..63 (B rows)
    const int skB = ((((tid >> 4) & 3) << 3) | ((tid >> 8) << 5)); // 0..56
    const int bslot = (tid & 255) * 8 + (tid >> 8) * 2048;

    const u16* aRow = Ab + (long)(m0 + srow) * lda + sk0;
    if (ASEL) {
        const int* selm = seg ? p.selm2 : p.selm1;
        const int* seli = seg ? p.seli2 : p.seli1;
        const int r0 = m0 + srow;
        if (selm[r0]) aRow = p.DG + (long)(((r0 >> 9) << 3) + seli[r0]) * 512 + sk0;
    }
    const u16* bRow = Bb + (long)(n0 + srB) * ldb + skB;

    auto stage = [&](int kb2) {
        short* base = &LS[(kb2 & 1) * 12288];
        const int kk = kb2 << 6;
        glds16(aRow + kk,      &base[slot]);
        glds16(aRow + kk + 32, &base[4096 + slot]);
        glds16(bRow + kk,      &base[8192 + bslot]);
    };

    const int wave = tid >> 6, lane = tid & 63;
    const int gA = (wave >> 1) << 1;   // A group base (16-row units)
    const int gB = (wave & 1) << 1;    // B group base

    f32x4 acc[2][2] = {};
    const int nkb = p.K >> 6;

    stage(0);
    for (int kb = 0; kb < nkb; ++kb) {
        if (kb + 1 < nkb) {
            stage(kb + 1);
            asm volatile("s_waitcnt vmcnt(3)" ::: "memory");   // own stage(kb) done; stage(kb+1) in flight
        } else {
            asm volatile("s_waitcnt vmcnt(0)" ::: "memory");   // final: drain
        }
        __builtin_amdgcn_s_barrier();   // all waves' stage(kb) complete
        const short* ls = &LS[(kb & 1) * 12288];
#pragma unroll
        for (int kh = 0; kh < 2; ++kh) {
            s16x8 aF[2], bF[2];
#pragma unroll
            for (int mt = 0; mt < 2; ++mt) aF[mt] = *(const s16x8*)&ls[kh * 4096 + ((gA + mt) * 64 + lane) * 8];
#pragma unroll
            for (int nt = 0; nt < 2; ++nt) bF[nt] = *(const s16x8*)&ls[8192 + kh * 2048 + ((gB + nt) * 64 + lane) * 8];
#pragma unroll
            for (int mt = 0; mt < 2; ++mt)
#pragma unroll
                for (int nt = 0; nt < 2; ++nt)
                    acc[mt][nt] = __builtin_amdgcn_mfma_f32_16x16x32_bf16(aF[mt], bF[nt], acc[mt][nt], 0, 0, 0);
        }
        __builtin_amdgcn_s_barrier();   // readers of buf kb&1 done -> reusable
    }

    // ---- epilogue ----
    const int ml = lane & 15, quad = lane >> 4;
    const int wm = (wave >> 1) * 32, wn = (wave & 1) * 32;
    u16* Cb16 = (u16*)(seg ? p.C2 : p.C1);
    float* Cb32 = (float*)(seg ? p.C2 : p.C1);
    const int haveC = (seg ? p.C2 : p.C1) != nullptr;
    const int obf = seg ? p.obf2 : p.obf1;
    const int ldc = seg ? p.ldc2 : p.ldc1;
    if (haveC) { if (obf) Cb16 += z * p.sC; else Cb32 += z * p.sC; }
    u16* CTb = seg ? p.CT2 : p.CT1;
    if (CTb) CTb += z * p.sCT;
    const u16* CiT = (const u16*)(seg ? p.Ci2 : p.Ci1);
    const float* Ci32 = (const float*)(seg ? p.Ci2 : p.Ci1);
    const int cm = seg ? p.cm2 : p.cm1;
    const int ldci = seg ? p.ldci2 : p.ldci1;
    {
        const long sCi = seg ? p.sCi2 : p.sCi1;
        if (cm) CiT += z * sCi; else Ci32 += z * sCi;
    }
    const float pal = (EPI == 4) ? p.prelu[p.pidx] : 0.0f;
    const float* scp = (EPI == 8) ? (seg ? p.sc2 : p.sc1) : nullptr;
    const int* eselm = (EPI == 8) ? (seg ? p.selm2 : p.selm1) : nullptr;
    const int* eseli2 = (EPI == 8) ? (seg ? p.seli2 : p.seli1) : nullptr;

    const bool useEp = haveC && (obf == 1);
    u16* Lds = (u16*)LS;
    const int bb = m0 >> 9, ss = m0 & 511;
    const int cd = tid >> 3, cso = (tid & 7) * 16;     // [64][128] coop coords (Ci/CT)

    // ---- phase Ci: coalesced Cin ----
    float cinAll[4][4];
    if (EPI == 3 || EPI == 4 || EPI == 7 || EPI == 8) {
        if (cm) {
            __syncthreads();
            const u16* srcc = CiT + (long)bb * SD_ + (long)(n0 + cd) * 512 + ss + cso;
            u16* dstc = &Lds[cd * 136 + cso];
#pragma unroll
            for (int j = 0; j < 2; ++j) *(s16x8*)&dstc[j * 8] = *(const s16x8*)&srcc[j * 8];
            __syncthreads();
#pragma unroll
            for (int mt = 0; mt < 2; ++mt)
#pragma unroll
                for (int nt = 0; nt < 2; ++nt) {
                    const ushort4 c4 = *(const ushort4*)&Lds[(wn + nt * 16 + ml) * 136 + wm + mt * 16 + quad * 4];
                    cinAll[mt * 2 + nt][0] = bf2f(c4.x); cinAll[mt * 2 + nt][1] = bf2f(c4.y);
                    cinAll[mt * 2 + nt][2] = bf2f(c4.z); cinAll[mt * 2 + nt][3] = bf2f(c4.w);
                }
        } else {
#pragma unroll
            for (int mt = 0; mt < 2; ++mt)
#pragma unroll
                for (int nt = 0; nt < 2; ++nt) {
                    const int col = n0 + wn + nt * 16 + ml;
                    const int rowb = m0 + wm + mt * 16 + quad * 4;
#pragma unroll
                    for (int r = 0; r < 4; ++r) cinAll[mt * 2 + nt][r] = Ci32[(long)(rowb + r) * ldci + col];
                }
        }
    }

    // ---- compute ----
    u16 pkAll[4][4];
#pragma unroll
    for (int mt = 0; mt < 2; ++mt) {
#pragma unroll
        for (int nt = 0; nt < 2; ++nt) {
            const int col = n0 + wn + nt * 16 + ml;
            const int rowb = m0 + wm + mt * 16 + quad * 4;
#pragma unroll
            for (int r = 0; r < 4; ++r) {
                const int row = rowb + r;
                float x = acc[mt][nt][r];
                if (EPI == 1) x += p.bias[col];
                else if (EPI == 3) x += cinAll[mt * 2 + nt][r];
                else if (EPI == 4) {
                    x = (x + p.bS * p.bias[col] + cinAll[mt * 2 + nt][r]) * p.invden[z * p.M + row];
                    x = (x >= 0.0f) ? x : pal * x;
                }
                else if (EPI == 6) x = sigmoidf_(x + p.bias[col]);
                else if (EPI == 7) x += p.bias[col] + cinAll[mt * 2 + nt][r];
                else if (EPI == 8) {
                    float av;
                    if (eselm[row]) av = bf2f(p.DG[(long)(((row >> 9) << 3) + eseli2[row]) * 512 + col]);
                    else av = bf2f(Ab[(long)row * lda + col]);
                    x = sigmoidf_(x + cinAll[mt * 2 + nt][r]) * scp[row] * av;
                }
                if (haveC && obf == 0) Cb32[(long)row * ldc + col] = x;
                pkAll[mt * 2 + nt][r] = f2bf(x);
            }
        }
    }

    // ---- phase CT: transposed store via LDS, coalesced drain ----
    if (CTb) {
        __syncthreads();
#pragma unroll
        for (int mt = 0; mt < 2; ++mt)
#pragma unroll
            for (int nt = 0; nt < 2; ++nt)
                *(ushort4*)&Lds[(wn + nt * 16 + ml) * 136 + wm + mt * 16 + quad * 4] =
                    *(const ushort4*)&pkAll[mt * 2 + nt][0];
        __syncthreads();
        u16* dstt = CTb + (long)bb * SD_ + (long)(n0 + cd) * 512 + ss + cso;
#pragma unroll
        for (int j = 0; j < 2; ++j) *(s16x8*)&dstt[j * 8] = *(const s16x8*)&Lds[cd * 136 + cso + j * 8];
    }

    // ---- phase C: bf16 normal store via LDS [128][72], coalesced drain ----
    if (useEp) {
        __syncthreads();
#pragma unroll
        for (int mt = 0; mt < 2; ++mt)
#pragma unroll
            for (int nt = 0; nt < 2; ++nt)
#pragma unroll
                for (int r = 0; r < 4; ++r)
                    Lds[(wm + mt * 16 + quad * 4 + r) * 72 + wn + nt * 16 + ml] = pkAll[mt * 2 + nt][r];
        __syncthreads();
        const int cd2 = tid >> 2, cso2 = (tid & 3) * 16;
#pragma unroll
        for (int j = 0; j < 2; ++j) {
            const s16x8 v = *(const s16x8*)&Lds[cd2 * 72 + cso2 + j * 8];
            *(s16x8*)&Cb16[(long)(m0 + cd2) * ldc + n0 + cso2 + j * 8] = v;
        }
    }
}

// --------------------------- pre-pass conversions ---------------------------
__global__ __launch_bounds__(256)
void cvt_k(const float* __restrict__ s, u16* __restrict__ d)
{
    const long i = ((long)blockIdx.x * 256 + threadIdx.x) * 4;
    const float4 v = *(const float4*)&s[i];
    ushort4 h = { f2bf(v.x), f2bf(v.y), f2bf(v.z), f2bf(v.w) };
    *(ushort4*)&d[i] = h;
}

// batched transpose+cvt: src[z] RxC fp32 -> dstT[z] CxR bf16 (+ optional normal copy)
__global__ __launch_bounds__(256)
void trcvt_k(const float* __restrict__ src, u16* __restrict__ dstT, u16* __restrict__ dstN,
             const int R, const int C, const long sS, const long sDT, const long sDN)
{
    __shared__ u16 t[64][72];
    const float* s = src + blockIdx.z * sS;
    const int r0 = blockIdx.y * 64, c0 = blockIdx.x * 64;
    const int tid = threadIdx.x;
    const int lr = tid >> 2, lc4 = (tid & 3) * 16;
#pragma unroll
    for (int j = 0; j < 4; ++j) {
        const float4 v = *(const float4*)&s[(long)(r0 + lr) * C + c0 + lc4 + j * 4];
        ushort4 h = { f2bf(v.x), f2bf(v.y), f2bf(v.z), f2bf(v.w) };
        *(ushort4*)&t[lr][lc4 + j * 4] = h;
        if (dstN) *(ushort4*)&dstN[blockIdx.z * sDN + (long)(r0 + lr) * C + c0 + lc4 + j * 4] = h;
    }
    __syncthreads();
    const int lcol = tid >> 2, rc = (tid & 3) * 16;
#pragma unroll
    for (int j = 0; j < 2; ++j) {
        s16x8 v;
#pragma unroll
        for (int q = 0; q < 8; ++q) v[q] = (short)t[rc + j * 8 + q][lcol];
        *(s16x8*)&dstT[blockIdx.z * sDT + (long)(c0 + lcol) * R + r0 + rc + j * 8] = v;
    }
}

// ---------------------------------------------------------------------------
__global__ __launch_bounds__(256)
void e0_k(const float* __restrict__ adj, const float* __restrict__ depmap,
          const float* __restrict__ domain_id, const float* __restrict__ redomain_id,
          float* __restrict__ invden, float* __restrict__ fa, int* __restrict__ dcol,
          int* __restrict__ dm, int* __restrict__ dsel, int* __restrict__ rm, int* __restrict__ rsel)
{
    const int bs = blockIdx.x;
    const int t = threadIdx.x;
    const float* arow = adj + (long)bs * 512;
    const float* drow = depmap + (long)bs * 512;
    __shared__ float red[256];
    __shared__ int scol;
    if (t == 0) scol = 0;
    const float a0 = arow[t], a1 = arow[t + 256];
    const float p0 = drow[t], p1 = drow[t + 256];
    if (p0 > 0.5f) scol = t;
    if (p1 > 0.5f) scol = t + 256;
    red[t] = a0 + a1;
    __syncthreads();
    for (int off = 128; off > 0; off >>= 1) { if (t < off) red[t] += red[t + off]; __syncthreads(); }
    if (t == 0) invden[bs] = 1.0f / (red[0] + 1.0f);
    __syncthreads();
    red[t] = a0 * p0 + a1 * p1;
    __syncthreads();
    for (int off = 128; off > 0; off >>= 1) { if (t < off) red[t] += red[t + off]; __syncthreads(); }
    if (t == 0) {
        fa[bs] = red[0];
        dcol[bs] = scol;
        const float* q = domain_id + (long)bs * 8;
        float s = 0.f; int sel = 0;
        for (int k = 0; k < 8; ++k) { float v = q[k]; s += v; if (v > 0.5f) sel = k; }
        dm[bs] = (s > 0.5f) ? 1 : 0; dsel[bs] = sel;
        const float* r = redomain_id + (long)bs * 8;
        s = 0.f; sel = 0;
        for (int k = 0; k < 8; ++k) { float v = r[k]; s += v; if (v > 0.5f) sel = k; }
        rm[bs] = (s > 0.5f) ? 1 : 0; rsel[bs] = sel;
    }
}

__global__ void e0b_k(const float* __restrict__ adj, const int* __restrict__ dcol, float* __restrict__ ba)
{
    const int bs = blockIdx.x * 256 + threadIdx.x;
    const int b = bs >> 9, s = bs & 511;
    ba[bs] = adj[((long)b * 512 + dcol[bs]) * 512 + s];
}

// pool pass1 (chunked masked max) + OxR^T = (OUT .* rel)^T, all bf16
__global__ __launch_bounds__(256)
void pool1_k(const u16* __restrict__ OUT, const int ldO, const int* __restrict__ domain,
             const u16* __restrict__ relb, u16* __restrict__ cm, u16* __restrict__ OxRT)
{
    const int b = blockIdx.x >> 4, c = blockIdx.x & 15;
    const int s0 = c * 32, tid = threadIdx.x;
    __shared__ int dom[256];
    dom[tid] = domain[((long)(b * 512 + s0 + (tid >> 3))) * 8 + (tid & 7)];
    __syncthreads();
    const int d0 = tid * 2;
    float mxa[8], mxb[8];
#pragma unroll
    for (int k = 0; k < 8; ++k) { mxa[k] = -10000.0f; mxb[k] = -10000.0f; }
    s16x8 pA[4], pB[4];
#pragma unroll
    for (int s = 0; s < 32; ++s) {
        const int row = b * 512 + s0 + s;
        const unsigned uv = *(const unsigned*)&OUT[(long)row * ldO + d0];
        const unsigned rv = *(const unsigned*)&relb[(long)row * 512 + d0];
        const float vx = bf2f((u16)(uv & 0xffff)), vy = bf2f((u16)(uv >> 16));
        const float rx = bf2f((u16)(rv & 0xffff)), ry = bf2f((u16)(rv >> 16));
        pA[s >> 3][s & 7] = (short)f2bf(vx * rx);
        pB[s >> 3][s & 7] = (short)f2bf(vy * ry);
        const int* ds = &dom[s * 8];
#pragma unroll
        for (int k = 0; k < 8; ++k) {
            mxa[k] = fmaxf(mxa[k], ds[k] ? -10000.0f : vx);
            mxb[k] = fmaxf(mxb[k], ds[k] ? -10000.0f : vy);
        }
    }
#pragma unroll
    for (int j = 0; j < 4; ++j) *(s16x8*)&OxRT[((long)b * 512 + d0) * 512 + s0 + j * 8] = pA[j];
#pragma unroll
    for (int j = 0; j < 4; ++j) *(s16x8*)&OxRT[((long)b * 512 + d0 + 1) * 512 + s0 + j * 8] = pB[j];
#pragma unroll
    for (int k = 0; k < 8; ++k) {
        ushort2 h = { f2bf(mxa[k]), f2bf(mxb[k]) };
        *(ushort2*)&cm[((long)((b * 16 + c) * 8 + k)) * 512 + d0] = h;
    }
}

__global__ void pool2_k(const u16* __restrict__ cm, u16* __restrict__ pooled)
{
    const int q = blockIdx.x * 256 + threadIdx.x;      // 65536
    const int b = q >> 12, k = (q >> 9) & 7, d = q & 511;
    float m = -1e30f;
    for (int c = 0; c < 16; ++c)
        m = fmaxf(m, bf2f(cm[((long)((b * 16 + c) * 8 + k)) * 512 + d]));
    pooled[((long)(b * 8 + k)) * 512 + d] = f2bf(m);
}

extern "C" void kernel_launch(void* const* d_in, const int* in_sizes, int n_in,
                              void* d_out, int out_size, void* d_ws, size_t ws_size,
                              hipStream_t stream)
{
    const float* adj         = (const float*)d_in[0];
    const int*   domain      = (const int*)d_in[1];
    const float* domain_id   = (const float*)d_in[2];
    const float* redomain_id = (const float*)d_in[3];
    const float* frontrel    = (const float*)d_in[4];
    const float* backrel     = (const float*)d_in[5];
    const float* depmap      = (const float*)d_in[6];
    const float* rel         = (const float*)d_in[7];
    const float* gcn         = (const float*)d_in[8];
    const float* W_layers    = (const float*)d_in[10];
    const float* b_layers    = (const float*)d_in[11];
    const float* prelu_a     = (const float*)d_in[12];
    const float* W_dg        = (const float*)d_in[13];
    const float* b_dg        = (const float*)d_in[14];
    const float* W_mg        = (const float*)d_in[15];
    const float* b_mg        = (const float*)d_in[16];
    const float* W_out       = (const float*)d_in[17];
    const float* b_out       = (const float*)d_in[18];
    float* out = (float*)d_out;

    char* w = (char*)d_ws;
    auto alloc = [&](size_t bytes) { void* p = (void*)w; w += (bytes + 255) & ~(size_t)255; return p; };
    const size_t Bb = (size_t)BSD_ * 2;
    u16* OUTS_bf = (u16*)alloc((size_t)8192 * 1536 * 2);
    u16* OUTT    = (u16*)alloc(Bb);   // layer output transposed [b][d][s]
    u16* gcnT    = (u16*)alloc(Bb);
    u16* RB_bf   = (u16*)alloc(Bb);   // normal [b][s][d]
    u16* XBT     = (u16*)alloc(Bb);   // [b][d][s]
    u16* XFT     = (u16*)alloc(Bb);   // [b][d][s]
    u16* OxRT    = (u16*)alloc(Bb);
    u16* DLT     = (u16*)alloc(Bb);   // [b][d][s]
    u16* AXO_bf  = (u16*)alloc(Bb);   // normal
    u16* BBT     = (u16*)alloc(Bb);   // [b][d][s]
    u16* FBT     = (u16*)alloc(Bb);
    u16* rel_bf  = (u16*)alloc(Bb);
    u16* relT_bf = (u16*)alloc(Bb);
    u16* adj_bf  = (u16*)alloc(Bb);
    u16* gcn_bf  = (u16*)alloc(Bb);
    u16* frel_bf = (u16*)alloc(Bb);
    u16* brel_bf = (u16*)alloc(Bb);
    u16* WmgT1 = (u16*)alloc((size_t)SD_ * 2);
    u16* WmgT2 = (u16*)alloc((size_t)SD_ * 2);
    u16* WdgT  = (u16*)alloc((size_t)SD_ * 2);
    u16* WlT   = (u16*)alloc((size_t)3 * SD_ * 2);
    u16* WoutT = (u16*)alloc((size_t)512 * 1536 * 2);
    u16* cm     = (u16*)alloc((size_t)16 * 16 * 8 * 512 * 2);
    u16* pooled = (u16*)alloc((size_t)16 * 8 * 512 * 2);
    u16* DGb    = (u16*)alloc((size_t)16 * 8 * 512 * 2);   // bf16 domain gates
    float* invden = (float*)alloc(8192 * 4);
    float* fa     = (float*)alloc(8192 * 4);
    float* ba     = (float*)alloc(8192 * 4);
    int* dcol = (int*)alloc(8192 * 4);
    int* dm   = (int*)alloc(8192 * 4);
    int* dsel = (int*)alloc(8192 * 4);
    int* rm   = (int*)alloc(8192 * 4);
    int* rsel = (int*)alloc(8192 * 4);

    // ---- pre-pass ----
    cvt_k<<<4096, 256, 0, stream>>>(adj, adj_bf);
    cvt_k<<<4096, 256, 0, stream>>>(frontrel, frel_bf);
    cvt_k<<<4096, 256, 0, stream>>>(backrel, brel_bf);
    trcvt_k<<<dim3(8, 8, 16), 256, 0, stream>>>(gcn, gcnT, gcn_bf, 512, 512, SD_, SD_, SD_);
    trcvt_k<<<dim3(8, 8, 16), 256, 0, stream>>>(rel, relT_bf, rel_bf, 512, 512, SD_, SD_, SD_);
    trcvt_k<<<dim3(8, 8, 1), 256, 0, stream>>>(W_mg, WmgT1, nullptr, 512, 512, 0, 0, 0);
    trcvt_k<<<dim3(8, 8, 1), 256, 0, stream>>>(W_mg + SD_, WmgT2, nullptr, 512, 512, 0, 0, 0);
    trcvt_k<<<dim3(8, 8, 1), 256, 0, stream>>>(W_dg, WdgT, nullptr, 512, 512, 0, 0, 0);
    trcvt_k<<<dim3(8, 8, 3), 256, 0, stream>>>(W_layers, WlT, nullptr, 512, 512, SD_, SD_, 0);
    trcvt_k<<<dim3(8, 24, 1), 256, 0, stream>>>(W_out, WoutT, nullptr, 1536, 512, 0, 0, 0);
    e0_k<<<8192, 256, 0, stream>>>(adj, depmap, domain_id, redomain_id, invden, fa, dcol, dm, dsel, rm, rsel);
    e0b_k<<<32, 256, 0, stream>>>(adj, dcol, ba);

    const dim3 blk(512);

    // BBT/FBT = ({back,front}rel @ WmgT2 + b_mg)^T  (z=2 merged, 1024 blocks)
    {
        GP p{};
        p.A1 = brel_bf; p.A2 = frel_bf; p.lda1 = p.lda2 = 512; p.sA = 0;
        p.B1 = p.B2 = WmgT2; p.ldb1 = p.ldb2 = 512; p.sB = 0;
        p.CT1 = BBT; p.CT2 = FBT; p.sCT = 0;
        p.bias = b_mg; p.M = 8192; p.K = 512; p.zs = 1; p.swzX = 3; p.swzY = 6;
        gemm3<1, 0><<<dim3(8, 64, 2), blk, 0, stream>>>(p);
    }

    for (int l = 0; l < 3; ++l) {
        const u16* OUTp  = (l == 0) ? gcn_bf : (OUTS_bf + (l - 1) * 512);
        const u16* OUTTp = (l == 0) ? gcnT : OUTT;
        const int ldO = (l == 0) ? 512 : 1536;

        // RB = rel @ outputs (B = OUT^T)  (512 blocks -> 2/CU)
        {
            GP p{};
            p.A1 = rel_bf; p.lda1 = 512; p.sA = SD_;
            p.B1 = OUTTp; p.ldb1 = 512; p.sB = SD_;
            p.C1 = RB_bf; p.obf1 = 1; p.ldc1 = 512; p.sC = SD_;
            p.M = 512; p.K = 512; p.zs = 16; p.swzX = 3; p.swzY = 2;
            gemm3<0, 0><<<dim3(8, 4, 16), blk, 0, stream>>>(p);
        }
        pool1_k<<<256, 256, 0, stream>>>(OUTp, ldO, domain, rel_bf, cm, OxRT);
        pool2_k<<<256, 256, 0, stream>>>(cm, pooled);
        // DG = sigm(pooled @ WdgT + b_dg)  (bf16 out)
        {
            GP p{};
            p.A1 = pooled; p.lda1 = 512; p.B1 = WdgT; p.ldb1 = 512;
            p.C1 = DGb; p.obf1 = 1; p.ldc1 = 512;
            p.bias = b_dg; p.M = 128; p.K = 512; p.zs = 1; p.swzX = -1;
            gemm3<6, 0><<<dim3(8, 1, 1), blk, 0, stream>>>(p);
        }
        // gates (z=2): z0: XBT = (ba*sigm(RBeff@W1+BB)*RBeff)^T ; z1: XFT = (...)^T
        {
            GP p{};
            p.A1 = RB_bf; p.lda1 = 512; p.A2 = OUTp; p.lda2 = ldO; p.sA = 0;
            p.selm1 = rm; p.seli1 = rsel; p.selm2 = dm; p.seli2 = dsel; p.DG = DGb;
            p.B1 = p.B2 = WmgT1; p.ldb1 = p.ldb2 = 512; p.sB = 0;
            p.Ci1 = BBT; p.Ci2 = FBT; p.cm1 = p.cm2 = 1; p.ldci1 = p.ldci2 = 512; p.sCi1 = p.sCi2 = 0;
            p.CT1 = XBT; p.CT2 = XFT; p.sCT = 0;
            p.sc1 = ba; p.sc2 = fa; p.M = 8192; p.K = 512; p.zs = 1; p.swzX = 3; p.swzY = 6;
            gemm3<8, 1><<<dim3(8, 64, 2), blk, 0, stream>>>(p);
        }
        // merged z=32: z<16: DLT = (relT @ XF + XB)^T ; z>=16: AXO = adj @ OxR + OUT (normal)
        {
            GP p{};
            p.A1 = relT_bf; p.lda1 = 512; p.A2 = adj_bf; p.lda2 = 512; p.sA = SD_;
            p.B1 = XFT; p.ldb1 = 512;
            p.B2 = OxRT; p.ldb2 = 512; p.sB = SD_;
            p.Ci1 = XBT; p.cm1 = 1; p.ldci1 = 512; p.sCi1 = SD_;
            p.Ci2 = OUTTp; p.cm2 = 1; p.ldci2 = 512; p.sCi2 = SD_;
            p.CT1 = DLT; p.sCT = SD_;
            p.C2 = AXO_bf; p.obf2 = 1; p.ldc2 = 512; p.sC = SD_;
            p.M = 512; p.K = 512; p.zs = 16; p.swzX = 3; p.swzY = 2;
            gemm3<3, 0><<<dim3(8, 4, 32), blk, 0, stream>>>(p);
        }
        // outs[l] = PReLU((AXO@W + 2b + DL)*invden) -> OUTS stripe (coalesced) + OUTT (transposed)
        {
            GP p{};
            p.A1 = AXO_bf; p.lda1 = 512; p.sA = SD_;
            p.B1 = WlT + (long)l * SD_; p.ldb1 = 512; p.sB = 0;
            p.Ci1 = DLT; p.cm1 = 1; p.ldci1 = 512; p.sCi1 = SD_;
            p.C1 = OUTS_bf + l * 512; p.obf1 = 1; p.ldc1 = 1536; p.sC = (long)512 * 1536;
            p.CT1 = OUTT; p.sCT = SD_;
            p.bias = b_layers + l * 512; p.bS = 2.0f;
            p.invden = invden; p.prelu = prelu_a; p.pidx = l;
            p.M = 512; p.K = 512; p.zs = 16; p.swzX = 3; p.swzY = 2;
            gemm3<4, 0><<<dim3(8, 4, 16), blk, 0, stream>>>(p);
        }
    }

    // out = OUTS @ W_out + b_out + gcn   (K=1536, fp32 direct, 512 blocks)
    {
        GP p{};
        p.A1 = OUTS_bf; p.lda1 = 1536; p.sA = 0;
        p.B1 = WoutT; p.ldb1 = 1536; p.sB = 0;
        p.Ci1 = gcn; p.cm1 = 0; p.ldci1 = 512; p.sCi1 = 0;
        p.C1 = out; p.obf1 = 0; p.ldc1 = 512; p.sC = 0;
        p.bias = b_out; p.M = 8192; p.K = 1536; p.zs = 1; p.swzX = 3; p.swzY = 6;
        gemm3<7, 0><<<dim3(8, 64, 1), blk, 0, stream>>>(p);
    }
}

// Round 10
// 624.197 us; speedup vs baseline: 1.0314x; 1.0314x over previous
//
#include <hip/hip_runtime.h>
#include <math.h>

#define SD_  (512*512)
#define BSD_ (16*512*512)

typedef unsigned short u16;
typedef short s16x8 __attribute__((ext_vector_type(8)));
typedef float f32x4 __attribute__((ext_vector_type(4)));

__device__ __forceinline__ float sigmoidf_(float x) { return 1.0f / (1.0f + __expf(-x)); }

__device__ __forceinline__ u16 f2bf(float f) {
    unsigned int u = __float_as_uint(f);
    u += 0x7fffu + ((u >> 16) & 1u);
    return (u16)(u >> 16);
}
__device__ __forceinline__ float bf2f(u16 h) { return __uint_as_float((unsigned)h << 16); }

__device__ __forceinline__ void glds16(const void* g, void* l) {
    __builtin_amdgcn_global_load_lds((const __attribute__((address_space(1))) unsigned int*)g,
                                     (__attribute__((address_space(3))) unsigned int*)l, 16, 0, 0);
}

// ---------------------------------------------------------------------------
// bf16 MFMA GEMM v14: HYBRID TILE. Template TN in {128, 64}; M-tile 128,
// BK=64, 512 thr = 8 waves, 2 LDS buffers, counted-vmcnt schedule (R5):
// stage(k+1); s_waitcnt vmcnt(GLDS) certifies own stage(k) while stage(k+1)
// stays in flight; barrier; compute; barrier.
//  TN=128 (R7 cfg, best for M=8192/z-merged dispatches: 512 blk = 2/CU,
//          16 B/output-elem): 4 glds/stage, wave 64x32, acc[4][2], 64 KB.
//  TN=64  (R9 cfg, for M=512 z=16 dispatches where TN=128 gives only
//          256 blk = 1/CU): 3 glds/stage, wave 32x32, acc[2][2], 48 KB.
// R9 A/B: big dispatches prefer TN=128 (42.5 vs 46.6 us); RB/outs prefer
// TN=64 (2/CU vs 1/CU). Coalesced epilogue (R7) in both geometries; NEW:
// EPI=7 fp32-Cin (final gemm) coalesced via LDS float[128][68] in two
// 64-col halves (was 16 scalar loads/thread @ 2KB stride).
// EPI: 0=store 1=+bias 3=+Cin 4=PReLU((acc+bS*bias+Cin)*invden) 6=sigm(+bias)
//      7=+bias+Cin 8=gate: sigm(acc+Cin)*sc[row]*Aeff(row,col)
// ASEL: DG bf16 -> per-thread A source POINTER select only.
// ---------------------------------------------------------------------------
struct GP {
    const u16 *A1, *A2;  int lda1, lda2;  long sA;
    const u16 *B1, *B2;  int ldb1, ldb2;  long sB;
    void *C1, *C2;  int obf1, obf2, ldc1, ldc2;  long sC;   // obf: 0=fp32 direct, 1=bf16 LDS-coalesced
    u16 *CT1, *CT2;  long sCT;                              // transposed [b][d][s] (ld=512, batch SD_)
    const void *Ci1, *Ci2;  int cm1, cm2, ldci1, ldci2;  long sCi1, sCi2;  // cm: 0=fp32 normal, 1=bf16 transposed
    const float *bias;  float bS;
    const float *sc1, *sc2;
    const int *selm1, *seli1, *selm2, *seli2;
    const u16 *DG;                                          // bf16 [B*8][512]
    const float *invden, *prelu;  int pidx;
    int M, K, zs, swzX, swzY;
};

template<int EPI, int ASEL, int TN>
__global__ __launch_bounds__(512, 4)
void gemm3(const GP p)
{
    __shared__ short LS[(TN == 128) ? 32768 : 24576];
    constexpr int BUFS = (TN == 128) ? 16384 : 12288;   // shorts per buffer
    constexpr int BKH  = (TN == 128) ? 4096 : 2048;     // B kh stride (shorts)
    constexpr int MW   = (TN == 128) ? 4 : 2;           // M frags per wave
    const int tid = threadIdx.x;
    int bx, by, bz;
    if (p.swzX >= 0) {
        const int bid = blockIdx.x + gridDim.x * (blockIdx.y + gridDim.y * blockIdx.z);
        const int ppx = (gridDim.y * gridDim.z) >> 3;
        const int xcd = bid & 7, idx = bid >> 3;
        const int pair = xcd * ppx + (idx >> p.swzX);
        bx = idx & ((1 << p.swzX) - 1);
        by = pair & ((1 << p.swzY) - 1);
        bz = pair >> p.swzY;
    } else { bx = blockIdx.x; by = blockIdx.y; bz = blockIdx.z; }

    const int seg = (bz >= p.zs) ? 1 : 0;
    const int z = seg ? bz - p.zs : bz;
    const u16* Ab = (seg ? p.A2 : p.A1) + z * p.sA;
    const int lda = seg ? p.lda2 : p.lda1;
    const u16* Bb = (seg ? p.B2 : p.B1) + z * p.sB;
    const int ldb = seg ? p.ldb2 : p.ldb1;

    const int m0 = by * 128, n0 = bx * TN;
    const int srow = ((tid >> 6) << 4) | (tid & 15);   // 0..127 (A rows)
    const int sk0 = ((tid >> 4) & 3) << 3;             // 0,8,16,24
    const int slot = ((srow >> 4) << 9) + (sk0 << 4) + ((srow & 15) << 3);
    // TN=64 B-staging coords
    const int srB = (((tid >> 6) & 3) << 4) | (tid & 15);
    const int skB = ((((tid >> 4) & 3) << 3) | ((tid >> 8) << 5));
    const int bslot = (tid & 255) * 8 + (tid >> 8) * 2048;

    const u16* aRow = Ab + (long)(m0 + srow) * lda + sk0;
    if (ASEL) {
        const int* selm = seg ? p.selm2 : p.selm1;
        const int* seli = seg ? p.seli2 : p.seli1;
        const int r0 = m0 + srow;
        if (selm[r0]) aRow = p.DG + (long)(((r0 >> 9) << 3) + seli[r0]) * 512 + sk0;
    }
    const u16* bRow = (TN == 128) ? (Bb + (long)(n0 + srow) * ldb + sk0)
                                  : (Bb + (long)(n0 + srB) * ldb + skB);

    auto stage = [&](int kb2) {
        short* base = &LS[(kb2 & 1) * BUFS];
        const int kk = kb2 << 6;
        glds16(aRow + kk,      &base[slot]);
        glds16(aRow + kk + 32, &base[4096 + slot]);
        if (TN == 128) {
            glds16(bRow + kk,      &base[8192 + slot]);
            glds16(bRow + kk + 32, &base[12288 + slot]);
        } else {
            glds16(bRow + kk, &base[8192 + bslot]);
        }
    };

    const int wave = tid >> 6, lane = tid & 63;
    const int gA = (TN == 128) ? ((wave >> 2) << 2) : ((wave >> 1) << 1);
    const int gB = (TN == 128) ? ((wave & 3) << 1) : ((wave & 1) << 1);

    f32x4 acc[MW][2] = {};
    const int nkb = p.K >> 6;

    stage(0);
    for (int kb = 0; kb < nkb; ++kb) {
        if (kb + 1 < nkb) {
            stage(kb + 1);
            if (TN == 128) asm volatile("s_waitcnt vmcnt(4)" ::: "memory");
            else           asm volatile("s_waitcnt vmcnt(3)" ::: "memory");
        } else {
            asm volatile("s_waitcnt vmcnt(0)" ::: "memory");
        }
        __builtin_amdgcn_s_barrier();   // all waves' stage(kb) complete
        const short* ls = &LS[(kb & 1) * BUFS];
#pragma unroll
        for (int kh = 0; kh < 2; ++kh) {
            s16x8 aF[MW], bF[2];
#pragma unroll
            for (int mt = 0; mt < MW; ++mt) aF[mt] = *(const s16x8*)&ls[kh * 4096 + ((gA + mt) * 64 + lane) * 8];
#pragma unroll
            for (int nt = 0; nt < 2; ++nt) bF[nt] = *(const s16x8*)&ls[8192 + kh * BKH + ((gB + nt) * 64 + lane) * 8];
#pragma unroll
            for (int mt = 0; mt < MW; ++mt)
#pragma unroll
                for (int nt = 0; nt < 2; ++nt)
                    acc[mt][nt] = __builtin_amdgcn_mfma_f32_16x16x32_bf16(aF[mt], bF[nt], acc[mt][nt], 0, 0, 0);
        }
        __builtin_amdgcn_s_barrier();   // readers of buf kb&1 done -> reusable
    }

    // ---- epilogue ----
    const int ml = lane & 15, quad = lane >> 4;
    const int wm = (TN == 128) ? ((wave >> 2) * 64) : ((wave >> 1) * 32);
    const int wn = (TN == 128) ? ((wave & 3) * 32) : ((wave & 1) * 32);
    u16* Cb16 = (u16*)(seg ? p.C2 : p.C1);
    float* Cb32 = (float*)(seg ? p.C2 : p.C1);
    const int haveC = (seg ? p.C2 : p.C1) != nullptr;
    const int obf = seg ? p.obf2 : p.obf1;
    const int ldc = seg ? p.ldc2 : p.ldc1;
    if (haveC) { if (obf) Cb16 += z * p.sC; else Cb32 += z * p.sC; }
    u16* CTb = seg ? p.CT2 : p.CT1;
    if (CTb) CTb += z * p.sCT;
    const u16* CiT = (const u16*)(seg ? p.Ci2 : p.Ci1);
    const float* Ci32 = (const float*)(seg ? p.Ci2 : p.Ci1);
    const int cm = seg ? p.cm2 : p.cm1;
    const int ldci = seg ? p.ldci2 : p.ldci1;
    {
        const long sCi = seg ? p.sCi2 : p.sCi1;
        if (cm) CiT += z * sCi; else Ci32 += z * sCi;
    }
    const float pal = (EPI == 4) ? p.prelu[p.pidx] : 0.0f;
    const float* scp = (EPI == 8) ? (seg ? p.sc2 : p.sc1) : nullptr;
    const int* eselm = (EPI == 8) ? (seg ? p.selm2 : p.selm1) : nullptr;
    const int* eseli2 = (EPI == 8) ? (seg ? p.seli2 : p.seli1) : nullptr;

    const bool useEp = haveC && (obf == 1);
    u16* Lds = (u16*)LS;
    const int bb = m0 >> 9, ss = m0 & 511;
    // coop coords for [TN][128] Ci/CT tiles
    const int cd  = (TN == 128) ? (tid >> 2) : (tid >> 3);
    const int cso = (TN == 128) ? ((tid & 3) * 32) : ((tid & 7) * 16);
    constexpr int CJ = (TN == 128) ? 4 : 2;

    // ---- phase Ci: coalesced Cin ----
    float cinAll[MW * 2][4];
    if (EPI == 3 || EPI == 4 || EPI == 7 || EPI == 8) {
        if (cm) {
            __syncthreads();   // K-loop LDS done
            const u16* srcc = CiT + (long)bb * SD_ + (long)(n0 + cd) * 512 + ss + cso;
            u16* dstc = &Lds[cd * 136 + cso];
#pragma unroll
            for (int j = 0; j < CJ; ++j) *(s16x8*)&dstc[j * 8] = *(const s16x8*)&srcc[j * 8];
            __syncthreads();
#pragma unroll
            for (int mt = 0; mt < MW; ++mt)
#pragma unroll
                for (int nt = 0; nt < 2; ++nt) {
                    const ushort4 c4 = *(const ushort4*)&Lds[(wn + nt * 16 + ml) * 136 + wm + mt * 16 + quad * 4];
                    cinAll[mt * 2 + nt][0] = bf2f(c4.x); cinAll[mt * 2 + nt][1] = bf2f(c4.y);
                    cinAll[mt * 2 + nt][2] = bf2f(c4.z); cinAll[mt * 2 + nt][3] = bf2f(c4.w);
                }
        } else if (EPI == 7 && TN == 128) {
            // fp32 Cin coalesced via LDS float[128][68], two 64-col halves
            float* Lf = (float*)LS;
            const int lr = tid >> 2, lc = (tid & 3) * 16;
#pragma unroll
            for (int h = 0; h < 2; ++h) {
                __syncthreads();
                const float* src = Ci32 + (long)(m0 + lr) * ldci + n0 + h * 64 + lc;
                float* dst = &Lf[lr * 68 + lc];
#pragma unroll
                for (int j = 0; j < 4; ++j) *(float4*)&dst[j * 4] = *(const float4*)&src[j * 4];
                __syncthreads();
#pragma unroll
                for (int mt = 0; mt < MW; ++mt)
#pragma unroll
                    for (int nt = 0; nt < 2; ++nt) {
                        const int colL = wn + nt * 16 + ml;
                        if ((colL >> 6) == h) {
#pragma unroll
                            for (int r = 0; r < 4; ++r)
                                cinAll[mt * 2 + nt][r] = Lf[(wm + mt * 16 + quad * 4 + r) * 68 + (colL & 63)];
                        }
                    }
            }
        } else {
#pragma unroll
            for (int mt = 0; mt < MW; ++mt)
#pragma unroll
                for (int nt = 0; nt < 2; ++nt) {
                    const int col = n0 + wn + nt * 16 + ml;
                    const int rowb = m0 + wm + mt * 16 + quad * 4;
#pragma unroll
                    for (int r = 0; r < 4; ++r) cinAll[mt * 2 + nt][r] = Ci32[(long)(rowb + r) * ldci + col];
                }
        }
    }

    // ---- compute ----
    u16 pkAll[MW * 2][4];
#pragma unroll
    for (int mt = 0; mt < MW; ++mt) {
#pragma unroll
        for (int nt = 0; nt < 2; ++nt) {
            const int col = n0 + wn + nt * 16 + ml;
            const int rowb = m0 + wm + mt * 16 + quad * 4;
#pragma unroll
            for (int r = 0; r < 4; ++r) {
                const int row = rowb + r;
                float x = acc[mt][nt][r];
                if (EPI == 1) x += p.bias[col];
                else if (EPI == 3) x += cinAll[mt * 2 + nt][r];
                else if (EPI == 4) {
                    x = (x + p.bS * p.bias[col] + cinAll[mt * 2 + nt][r]) * p.invden[z * p.M + row];
                    x = (x >= 0.0f) ? x : pal * x;
                }
                else if (EPI == 6) x = sigmoidf_(x + p.bias[col]);
                else if (EPI == 7) x += p.bias[col] + cinAll[mt * 2 + nt][r];
                else if (EPI == 8) {
                    float av;
                    if (eselm[row]) av = bf2f(p.DG[(long)(((row >> 9) << 3) + eseli2[row]) * 512 + col]);
                    else av = bf2f(Ab[(long)row * lda + col]);
                    x = sigmoidf_(x + cinAll[mt * 2 + nt][r]) * scp[row] * av;
                }
                if (haveC && obf == 0) Cb32[(long)row * ldc + col] = x;
                pkAll[mt * 2 + nt][r] = f2bf(x);
            }
        }
    }

    // ---- phase CT: transposed store via LDS, coalesced drain ----
    if (CTb) {
        __syncthreads();
#pragma unroll
        for (int mt = 0; mt < MW; ++mt)
#pragma unroll
            for (int nt = 0; nt < 2; ++nt)
                *(ushort4*)&Lds[(wn + nt * 16 + ml) * 136 + wm + mt * 16 + quad * 4] =
                    *(const ushort4*)&pkAll[mt * 2 + nt][0];
        __syncthreads();
        u16* dstt = CTb + (long)bb * SD_ + (long)(n0 + cd) * 512 + ss + cso;
#pragma unroll
        for (int j = 0; j < CJ; ++j) *(s16x8*)&dstt[j * 8] = *(const s16x8*)&Lds[cd * 136 + cso + j * 8];
    }

    // ---- phase C: bf16 normal store via LDS, coalesced drain ----
    if (useEp) {
        constexpr int LDC2 = (TN == 128) ? 136 : 72;
        __syncthreads();
#pragma unroll
        for (int mt = 0; mt < MW; ++mt)
#pragma unroll
            for (int nt = 0; nt < 2; ++nt)
#pragma unroll
                for (int r = 0; r < 4; ++r)
                    Lds[(wm + mt * 16 + quad * 4 + r) * LDC2 + wn + nt * 16 + ml] = pkAll[mt * 2 + nt][r];
        __syncthreads();
        const int cd2 = tid >> 2, cso2 = (tid & 3) * (TN == 128 ? 32 : 16);
#pragma unroll
        for (int j = 0; j < CJ; ++j) {
            const s16x8 v = *(const s16x8*)&Lds[cd2 * LDC2 + cso2 + j * 8];
            *(s16x8*)&Cb16[(long)(m0 + cd2) * ldc + n0 + cso2 + j * 8] = v;
        }
    }
}

// --------------------------- pre-pass conversions ---------------------------
__global__ __launch_bounds__(256)
void cvt3_k(const float* __restrict__ s0, const float* __restrict__ s1, const float* __restrict__ s2,
            u16* __restrict__ d0, u16* __restrict__ d1, u16* __restrict__ d2)
{
    const int g = blockIdx.x >> 12;
    const float* s = (g == 0) ? s0 : (g == 1) ? s1 : s2;
    u16* d = (g == 0) ? d0 : (g == 1) ? d1 : d2;
    const long i = ((long)(blockIdx.x & 4095) * 256 + threadIdx.x) * 4;
    const float4 v = *(const float4*)&s[i];
    ushort4 h = { f2bf(v.x), f2bf(v.y), f2bf(v.z), f2bf(v.w) };
    *(ushort4*)&d[i] = h;
}

// batched transpose+cvt: src[z] RxC fp32 -> dstT[z] CxR bf16 (+ optional normal copy)
__global__ __launch_bounds__(256)
void trcvt_k(const float* __restrict__ src, u16* __restrict__ dstT, u16* __restrict__ dstN,
             const int R, const int C, const long sS, const long sDT, const long sDN)
{
    __shared__ u16 t[64][72];
    const float* s = src + blockIdx.z * sS;
    const int r0 = blockIdx.y * 64, c0 = blockIdx.x * 64;
    const int tid = threadIdx.x;
    const int lr = tid >> 2, lc4 = (tid & 3) * 16;
#pragma unroll
    for (int j = 0; j < 4; ++j) {
        const float4 v = *(const float4*)&s[(long)(r0 + lr) * C + c0 + lc4 + j * 4];
        ushort4 h = { f2bf(v.x), f2bf(v.y), f2bf(v.z), f2bf(v.w) };
        *(ushort4*)&t[lr][lc4 + j * 4] = h;
        if (dstN) *(ushort4*)&dstN[blockIdx.z * sDN + (long)(r0 + lr) * C + c0 + lc4 + j * 4] = h;
    }
    __syncthreads();
    const int lcol = tid >> 2, rc = (tid & 3) * 16;
#pragma unroll
    for (int j = 0; j < 2; ++j) {
        s16x8 v;
#pragma unroll
        for (int q = 0; q < 8; ++q) v[q] = (short)t[rc + j * 8 + q][lcol];
        *(s16x8*)&dstT[blockIdx.z * sDT + (long)(c0 + lcol) * R + r0 + rc + j * 8] = v;
    }
}

// ---------------------------------------------------------------------------
__global__ __launch_bounds__(256)
void e0_k(const float* __restrict__ adj, const float* __restrict__ depmap,
          const float* __restrict__ domain_id, const float* __restrict__ redomain_id,
          float* __restrict__ invden, float* __restrict__ fa, int* __restrict__ dcol,
          int* __restrict__ dm, int* __restrict__ dsel, int* __restrict__ rm, int* __restrict__ rsel)
{
    const int bs = blockIdx.x;
    const int t = threadIdx.x;
    const float* arow = adj + (long)bs * 512;
    const float* drow = depmap + (long)bs * 512;
    __shared__ float red[256];
    __shared__ int scol;
    if (t == 0) scol = 0;
    const float a0 = arow[t], a1 = arow[t + 256];
    const float p0 = drow[t], p1 = drow[t + 256];
    if (p0 > 0.5f) scol = t;
    if (p1 > 0.5f) scol = t + 256;
    red[t] = a0 + a1;
    __syncthreads();
    for (int off = 128; off > 0; off >>= 1) { if (t < off) red[t] += red[t + off]; __syncthreads(); }
    if (t == 0) invden[bs] = 1.0f / (red[0] + 1.0f);
    __syncthreads();
    red[t] = a0 * p0 + a1 * p1;
    __syncthreads();
    for (int off = 128; off > 0; off >>= 1) { if (t < off) red[t] += red[t + off]; __syncthreads(); }
    if (t == 0) {
        fa[bs] = red[0];
        dcol[bs] = scol;
        const float* q = domain_id + (long)bs * 8;
        float s = 0.f; int sel = 0;
        for (int k = 0; k < 8; ++k) { float v = q[k]; s += v; if (v > 0.5f) sel = k; }
        dm[bs] = (s > 0.5f) ? 1 : 0; dsel[bs] = sel;
        const float* r = redomain_id + (long)bs * 8;
        s = 0.f; sel = 0;
        for (int k = 0; k < 8; ++k) { float v = r[k]; s += v; if (v > 0.5f) sel = k; }
        rm[bs] = (s > 0.5f) ? 1 : 0; rsel[bs] = sel;
    }
}

__global__ void e0b_k(const float* __restrict__ adj, const int* __restrict__ dcol, float* __restrict__ ba)
{
    const int bs = blockIdx.x * 256 + threadIdx.x;
    const int b = bs >> 9, s = bs & 511;
    ba[bs] = adj[((long)b * 512 + dcol[bs]) * 512 + s];
}

// pool pass1 (chunked masked max) + OxR^T = (OUT .* rel)^T, all bf16
__global__ __launch_bounds__(256)
void pool1_k(const u16* __restrict__ OUT, const int ldO, const int* __restrict__ domain,
             const u16* __restrict__ relb, u16* __restrict__ cm, u16* __restrict__ OxRT)
{
    const int b = blockIdx.x >> 4, c = blockIdx.x & 15;
    const int s0 = c * 32, tid = threadIdx.x;
    __shared__ int dom[256];
    dom[tid] = domain[((long)(b * 512 + s0 + (tid >> 3))) * 8 + (tid & 7)];
    __syncthreads();
    const int d0 = tid * 2;
    float mxa[8], mxb[8];
#pragma unroll
    for (int k = 0; k < 8; ++k) { mxa[k] = -10000.0f; mxb[k] = -10000.0f; }
    s16x8 pA[4], pB[4];
#pragma unroll
    for (int s = 0; s < 32; ++s) {
        const int row = b * 512 + s0 + s;
        const unsigned uv = *(const unsigned*)&OUT[(long)row * ldO + d0];
        const unsigned rv = *(const unsigned*)&relb[(long)row * 512 + d0];
        const float vx = bf2f((u16)(uv & 0xffff)), vy = bf2f((u16)(uv >> 16));
        const float rx = bf2f((u16)(rv & 0xffff)), ry = bf2f((u16)(rv >> 16));
        pA[s >> 3][s & 7] = (short)f2bf(vx * rx);
        pB[s >> 3][s & 7] = (short)f2bf(vy * ry);
        const int* ds = &dom[s * 8];
#pragma unroll
        for (int k = 0; k < 8; ++k) {
            mxa[k] = fmaxf(mxa[k], ds[k] ? -10000.0f : vx);
            mxb[k] = fmaxf(mxb[k], ds[k] ? -10000.0f : vy);
        }
    }
#pragma unroll
    for (int j = 0; j < 4; ++j) *(s16x8*)&OxRT[((long)b * 512 + d0) * 512 + s0 + j * 8] = pA[j];
#pragma unroll
    for (int j = 0; j < 4; ++j) *(s16x8*)&OxRT[((long)b * 512 + d0 + 1) * 512 + s0 + j * 8] = pB[j];
#pragma unroll
    for (int k = 0; k < 8; ++k) {
        ushort2 h = { f2bf(mxa[k]), f2bf(mxb[k]) };
        *(ushort2*)&cm[((long)((b * 16 + c) * 8 + k)) * 512 + d0] = h;
    }
}

__global__ void pool2_k(const u16* __restrict__ cm, u16* __restrict__ pooled)
{
    const int q = blockIdx.x * 256 + threadIdx.x;      // 65536
    const int b = q >> 12, k = (q >> 9) & 7, d = q & 511;
    float m = -1e30f;
    for (int c = 0; c < 16; ++c)
        m = fmaxf(m, bf2f(cm[((long)((b * 16 + c) * 8 + k)) * 512 + d]));
    pooled[((long)(b * 8 + k)) * 512 + d] = f2bf(m);
}

extern "C" void kernel_launch(void* const* d_in, const int* in_sizes, int n_in,
                              void* d_out, int out_size, void* d_ws, size_t ws_size,
                              hipStream_t stream)
{
    const float* adj         = (const float*)d_in[0];
    const int*   domain      = (const int*)d_in[1];
    const float* domain_id   = (const float*)d_in[2];
    const float* redomain_id = (const float*)d_in[3];
    const float* frontrel    = (const float*)d_in[4];
    const float* backrel     = (const float*)d_in[5];
    const float* depmap      = (const float*)d_in[6];
    const float* rel         = (const float*)d_in[7];
    const float* gcn         = (const float*)d_in[8];
    const float* W_layers    = (const float*)d_in[10];
    const float* b_layers    = (const float*)d_in[11];
    const float* prelu_a     = (const float*)d_in[12];
    const float* W_dg        = (const float*)d_in[13];
    const float* b_dg        = (const float*)d_in[14];
    const float* W_mg        = (const float*)d_in[15];
    const float* b_mg        = (const float*)d_in[16];
    const float* W_out       = (const float*)d_in[17];
    const float* b_out       = (const float*)d_in[18];
    float* out = (float*)d_out;

    char* w = (char*)d_ws;
    auto alloc = [&](size_t bytes) { void* p = (void*)w; w += (bytes + 255) & ~(size_t)255; return p; };
    const size_t Bb = (size_t)BSD_ * 2;
    u16* OUTS_bf = (u16*)alloc((size_t)8192 * 1536 * 2);
    u16* OUTT    = (u16*)alloc(Bb);   // layer output transposed [b][d][s]
    u16* gcnT    = (u16*)alloc(Bb);
    u16* RB_bf   = (u16*)alloc(Bb);   // normal [b][s][d]
    u16* XBT     = (u16*)alloc(Bb);   // [b][d][s]
    u16* XFT     = (u16*)alloc(Bb);   // [b][d][s]
    u16* OxRT    = (u16*)alloc(Bb);
    u16* DLT     = (u16*)alloc(Bb);   // [b][d][s]
    u16* AXO_bf  = (u16*)alloc(Bb);   // normal
    u16* BBT     = (u16*)alloc(Bb);   // [b][d][s]
    u16* FBT     = (u16*)alloc(Bb);
    u16* rel_bf  = (u16*)alloc(Bb);
    u16* relT_bf = (u16*)alloc(Bb);
    u16* adj_bf  = (u16*)alloc(Bb);
    u16* gcn_bf  = (u16*)alloc(Bb);
    u16* frel_bf = (u16*)alloc(Bb);
    u16* brel_bf = (u16*)alloc(Bb);
    u16* WmgT1 = (u16*)alloc((size_t)SD_ * 2);
    u16* WmgT2 = (u16*)alloc((size_t)SD_ * 2);
    u16* WdgT  = (u16*)alloc((size_t)SD_ * 2);
    u16* WlT   = (u16*)alloc((size_t)3 * SD_ * 2);
    u16* WoutT = (u16*)alloc((size_t)512 * 1536 * 2);
    u16* cm     = (u16*)alloc((size_t)16 * 16 * 8 * 512 * 2);
    u16* pooled = (u16*)alloc((size_t)16 * 8 * 512 * 2);
    u16* DGb    = (u16*)alloc((size_t)16 * 8 * 512 * 2);   // bf16 domain gates
    float* invden = (float*)alloc(8192 * 4);
    float* fa     = (float*)alloc(8192 * 4);
    float* ba     = (float*)alloc(8192 * 4);
    int* dcol = (int*)alloc(8192 * 4);
    int* dm   = (int*)alloc(8192 * 4);
    int* dsel = (int*)alloc(8192 * 4);
    int* rm   = (int*)alloc(8192 * 4);
    int* rsel = (int*)alloc(8192 * 4);

    // ---- pre-pass ----
    cvt3_k<<<12288, 256, 0, stream>>>(adj, frontrel, backrel, adj_bf, frel_bf, brel_bf);
    trcvt_k<<<dim3(8, 8, 16), 256, 0, stream>>>(gcn, gcnT, gcn_bf, 512, 512, SD_, SD_, SD_);
    trcvt_k<<<dim3(8, 8, 16), 256, 0, stream>>>(rel, relT_bf, rel_bf, 512, 512, SD_, SD_, SD_);
    trcvt_k<<<dim3(8, 8, 1), 256, 0, stream>>>(W_mg, WmgT1, nullptr, 512, 512, 0, 0, 0);
    trcvt_k<<<dim3(8, 8, 1), 256, 0, stream>>>(W_mg + SD_, WmgT2, nullptr, 512, 512, 0, 0, 0);
    trcvt_k<<<dim3(8, 8, 1), 256, 0, stream>>>(W_dg, WdgT, nullptr, 512, 512, 0, 0, 0);
    trcvt_k<<<dim3(8, 8, 3), 256, 0, stream>>>(W_layers, WlT, nullptr, 512, 512, SD_, SD_, 0);
    trcvt_k<<<dim3(8, 24, 1), 256, 0, stream>>>(W_out, WoutT, nullptr, 1536, 512, 0, 0, 0);
    e0_k<<<8192, 256, 0, stream>>>(adj, depmap, domain_id, redomain_id, invden, fa, dcol, dm, dsel, rm, rsel);
    e0b_k<<<32, 256, 0, stream>>>(adj, dcol, ba);

    const dim3 blk(512);

    // BBT/FBT = ({back,front}rel @ WmgT2 + b_mg)^T  (z=2 merged, 512 blocks, TN=128)
    {
        GP p{};
        p.A1 = brel_bf; p.A2 = frel_bf; p.lda1 = p.lda2 = 512; p.sA = 0;
        p.B1 = p.B2 = WmgT2; p.ldb1 = p.ldb2 = 512; p.sB = 0;
        p.CT1 = BBT; p.CT2 = FBT; p.sCT = 0;
        p.bias = b_mg; p.M = 8192; p.K = 512; p.zs = 1; p.swzX = 2; p.swzY = 6;
        gemm3<1, 0, 128><<<dim3(4, 64, 2), blk, 0, stream>>>(p);
    }

    for (int l = 0; l < 3; ++l) {
        const u16* OUTp  = (l == 0) ? gcn_bf : (OUTS_bf + (l - 1) * 512);
        const u16* OUTTp = (l == 0) ? gcnT : OUTT;
        const int ldO = (l == 0) ? 512 : 1536;

        // RB = rel @ outputs (B = OUT^T)  (TN=64 -> 512 blocks = 2/CU)
        {
            GP p{};
            p.A1 = rel_bf; p.lda1 = 512; p.sA = SD_;
            p.B1 = OUTTp; p.ldb1 = 512; p.sB = SD_;
            p.C1 = RB_bf; p.obf1 = 1; p.ldc1 = 512; p.sC = SD_;
            p.M = 512; p.K = 512; p.zs = 16; p.swzX = 3; p.swzY = 2;
            gemm3<0, 0, 64><<<dim3(8, 4, 16), blk, 0, stream>>>(p);
        }
        pool1_k<<<256, 256, 0, stream>>>(OUTp, ldO, domain, rel_bf, cm, OxRT);
        pool2_k<<<256, 256, 0, stream>>>(cm, pooled);
        // DG = sigm(pooled @ WdgT + b_dg)  (bf16 out, TN=64 -> 8 blocks)
        {
            GP p{};
            p.A1 = pooled; p.lda1 = 512; p.B1 = WdgT; p.ldb1 = 512;
            p.C1 = DGb; p.obf1 = 1; p.ldc1 = 512;
            p.bias = b_dg; p.M = 128; p.K = 512; p.zs = 1; p.swzX = -1;
            gemm3<6, 0, 64><<<dim3(8, 1, 1), blk, 0, stream>>>(p);
        }
        // gates (z=2): z0: XBT = (ba*sigm(RBeff@W1+BB)*RBeff)^T ; z1: XFT = (...)^T  (TN=128)
        {
            GP p{};
            p.A1 = RB_bf; p.lda1 = 512; p.A2 = OUTp; p.lda2 = ldO; p.sA = 0;
            p.selm1 = rm; p.seli1 = rsel; p.selm2 = dm; p.seli2 = dsel; p.DG = DGb;
            p.B1 = p.B2 = WmgT1; p.ldb1 = p.ldb2 = 512; p.sB = 0;
            p.Ci1 = BBT; p.Ci2 = FBT; p.cm1 = p.cm2 = 1; p.ldci1 = p.ldci2 = 512; p.sCi1 = p.sCi2 = 0;
            p.CT1 = XBT; p.CT2 = XFT; p.sCT = 0;
            p.sc1 = ba; p.sc2 = fa; p.M = 8192; p.K = 512; p.zs = 1; p.swzX = 2; p.swzY = 6;
            gemm3<8, 1, 128><<<dim3(4, 64, 2), blk, 0, stream>>>(p);
        }
        // merged z=32: z<16: DLT = (relT @ XF + XB)^T ; z>=16: AXO = adj @ OxR + OUT  (TN=128)
        {
            GP p{};
            p.A1 = relT_bf; p.lda1 = 512; p.A2 = adj_bf; p.lda2 = 512; p.sA = SD_;
            p.B1 = XFT; p.ldb1 = 512;
            p.B2 = OxRT; p.ldb2 = 512; p.sB = SD_;
            p.Ci1 = XBT; p.cm1 = 1; p.ldci1 = 512; p.sCi1 = SD_;
            p.Ci2 = OUTTp; p.cm2 = 1; p.ldci2 = 512; p.sCi2 = SD_;
            p.CT1 = DLT; p.sCT = SD_;
            p.C2 = AXO_bf; p.obf2 = 1; p.ldc2 = 512; p.sC = SD_;
            p.M = 512; p.K = 512; p.zs = 16; p.swzX = 2; p.swzY = 2;
            gemm3<3, 0, 128><<<dim3(4, 4, 32), blk, 0, stream>>>(p);
        }
        // outs[l] = PReLU((AXO@W + 2b + DL)*invden)  (TN=64 -> 512 blocks = 2/CU)
        {
            GP p{};
            p.A1 = AXO_bf; p.lda1 = 512; p.sA = SD_;
            p.B1 = WlT + (long)l * SD_; p.ldb1 = 512; p.sB = 0;
            p.Ci1 = DLT; p.cm1 = 1; p.ldci1 = 512; p.sCi1 = SD_;
            p.C1 = OUTS_bf + l * 512; p.obf1 = 1; p.ldc1 = 1536; p.sC = (long)512 * 1536;
            p.CT1 = OUTT; p.sCT = SD_;
            p.bias = b_layers + l * 512; p.bS = 2.0f;
            p.invden = invden; p.prelu = prelu_a; p.pidx = l;
            p.M = 512; p.K = 512; p.zs = 16; p.swzX = 3; p.swzY = 2;
            gemm3<4, 0, 64><<<dim3(8, 4, 16), blk, 0, stream>>>(p);
        }
    }

    // out = OUTS @ W_out + b_out + gcn   (K=1536, fp32 direct, TN=128)
    {
        GP p{};
        p.A1 = OUTS_bf; p.lda1 = 1536; p.sA = 0;
        p.B1 = WoutT; p.ldb1 = 1536; p.sB = 0;
        p.Ci1 = gcn; p.cm1 = 0; p.ldci1 = 512; p.sCi1 = 0;
        p.C1 = out; p.obf1 = 0; p.ldc1 = 512; p.sC = 0;
        p.bias = b_out; p.M = 8192; p.K = 1536; p.zs = 1; p.swzX = 2; p.swzY = 6;
        gemm3<7, 0, 128><<<dim3(4, 64, 1), blk, 0, stream>>>(p);
    }
}

// Round 11
// 614.712 us; speedup vs baseline: 1.0473x; 1.0154x over previous
//
#include <hip/hip_runtime.h>
#include <math.h>

#define SD_  (512*512)
#define BSD_ (16*512*512)

typedef unsigned short u16;
typedef short s16x8 __attribute__((ext_vector_type(8)));
typedef float f32x4 __attribute__((ext_vector_type(4)));

__device__ __forceinline__ float sigmoidf_(float x) { return 1.0f / (1.0f + __expf(-x)); }

__device__ __forceinline__ u16 f2bf(float f) {
    unsigned int u = __float_as_uint(f);
    u += 0x7fffu + ((u >> 16) & 1u);
    return (u16)(u >> 16);
}
__device__ __forceinline__ float bf2f(u16 h) { return __uint_as_float((unsigned)h << 16); }

__device__ __forceinline__ void glds16(const void* g, void* l) {
    __builtin_amdgcn_global_load_lds((const __attribute__((address_space(1))) unsigned int*)g,
                                     (__attribute__((address_space(3))) unsigned int*)l, 16, 0, 0);
}

// ---------------------------------------------------------------------------
// bf16 MFMA GEMM v14 (unchanged from R10): HYBRID TILE, TN in {128, 64};
// M-tile 128, BK=64, 512 thr = 8 waves, 2 LDS buffers, counted-vmcnt
// schedule; coalesced epilogue. R11 changes are PRE-PASS ONLY:
//   - e0_k absorbs adj->bf16 (adj was read by cvt AND e0; now one pass)
//   - gcn+rel transposes fused into one z=32 trcvt2 launch
//   - 5 weight transposes (WmgT1/WmgT2/WdgT/WlT*3) fused into one z=6 launch
// Pre-pass: 10 launches -> 6, -25 MB traffic.
// EPI: 0=store 1=+bias 3=+Cin 4=PReLU((acc+bS*bias+Cin)*invden) 6=sigm(+bias)
//      7=+bias+Cin 8=gate: sigm(acc+Cin)*sc[row]*Aeff(row,col)
// ASEL: DG bf16 -> per-thread A source POINTER select only.
// ---------------------------------------------------------------------------
struct GP {
    const u16 *A1, *A2;  int lda1, lda2;  long sA;
    const u16 *B1, *B2;  int ldb1, ldb2;  long sB;
    void *C1, *C2;  int obf1, obf2, ldc1, ldc2;  long sC;   // obf: 0=fp32 direct, 1=bf16 LDS-coalesced
    u16 *CT1, *CT2;  long sCT;                              // transposed [b][d][s] (ld=512, batch SD_)
    const void *Ci1, *Ci2;  int cm1, cm2, ldci1, ldci2;  long sCi1, sCi2;  // cm: 0=fp32 normal, 1=bf16 transposed
    const float *bias;  float bS;
    const float *sc1, *sc2;
    const int *selm1, *seli1, *selm2, *seli2;
    const u16 *DG;                                          // bf16 [B*8][512]
    const float *invden, *prelu;  int pidx;
    int M, K, zs, swzX, swzY;
};

template<int EPI, int ASEL, int TN>
__global__ __launch_bounds__(512, 4)
void gemm3(const GP p)
{
    __shared__ short LS[(TN == 128) ? 32768 : 24576];
    constexpr int BUFS = (TN == 128) ? 16384 : 12288;   // shorts per buffer
    constexpr int BKH  = (TN == 128) ? 4096 : 2048;     // B kh stride (shorts)
    constexpr int MW   = (TN == 128) ? 4 : 2;           // M frags per wave
    const int tid = threadIdx.x;
    int bx, by, bz;
    if (p.swzX >= 0) {
        const int bid = blockIdx.x + gridDim.x * (blockIdx.y + gridDim.y * blockIdx.z);
        const int ppx = (gridDim.y * gridDim.z) >> 3;
        const int xcd = bid & 7, idx = bid >> 3;
        const int pair = xcd * ppx + (idx >> p.swzX);
        bx = idx & ((1 << p.swzX) - 1);
        by = pair & ((1 << p.swzY) - 1);
        bz = pair >> p.swzY;
    } else { bx = blockIdx.x; by = blockIdx.y; bz = blockIdx.z; }

    const int seg = (bz >= p.zs) ? 1 : 0;
    const int z = seg ? bz - p.zs : bz;
    const u16* Ab = (seg ? p.A2 : p.A1) + z * p.sA;
    const int lda = seg ? p.lda2 : p.lda1;
    const u16* Bb = (seg ? p.B2 : p.B1) + z * p.sB;
    const int ldb = seg ? p.ldb2 : p.ldb1;

    const int m0 = by * 128, n0 = bx * TN;
    const int srow = ((tid >> 6) << 4) | (tid & 15);   // 0..127 (A rows)
    const int sk0 = ((tid >> 4) & 3) << 3;             // 0,8,16,24
    const int slot = ((srow >> 4) << 9) + (sk0 << 4) + ((srow & 15) << 3);
    // TN=64 B-staging coords
    const int srB = (((tid >> 6) & 3) << 4) | (tid & 15);
    const int skB = ((((tid >> 4) & 3) << 3) | ((tid >> 8) << 5));
    const int bslot = (tid & 255) * 8 + (tid >> 8) * 2048;

    const u16* aRow = Ab + (long)(m0 + srow) * lda + sk0;
    if (ASEL) {
        const int* selm = seg ? p.selm2 : p.selm1;
        const int* seli = seg ? p.seli2 : p.seli1;
        const int r0 = m0 + srow;
        if (selm[r0]) aRow = p.DG + (long)(((r0 >> 9) << 3) + seli[r0]) * 512 + sk0;
    }
    const u16* bRow = (TN == 128) ? (Bb + (long)(n0 + srow) * ldb + sk0)
                                  : (Bb + (long)(n0 + srB) * ldb + skB);

    auto stage = [&](int kb2) {
        short* base = &LS[(kb2 & 1) * BUFS];
        const int kk = kb2 << 6;
        glds16(aRow + kk,      &base[slot]);
        glds16(aRow + kk + 32, &base[4096 + slot]);
        if (TN == 128) {
            glds16(bRow + kk,      &base[8192 + slot]);
            glds16(bRow + kk + 32, &base[12288 + slot]);
        } else {
            glds16(bRow + kk, &base[8192 + bslot]);
        }
    };

    const int wave = tid >> 6, lane = tid & 63;
    const int gA = (TN == 128) ? ((wave >> 2) << 2) : ((wave >> 1) << 1);
    const int gB = (TN == 128) ? ((wave & 3) << 1) : ((wave & 1) << 1);

    f32x4 acc[MW][2] = {};
    const int nkb = p.K >> 6;

    stage(0);
    for (int kb = 0; kb < nkb; ++kb) {
        if (kb + 1 < nkb) {
            stage(kb + 1);
            if (TN == 128) asm volatile("s_waitcnt vmcnt(4)" ::: "memory");
            else           asm volatile("s_waitcnt vmcnt(3)" ::: "memory");
        } else {
            asm volatile("s_waitcnt vmcnt(0)" ::: "memory");
        }
        __builtin_amdgcn_s_barrier();   // all waves' stage(kb) complete
        const short* ls = &LS[(kb & 1) * BUFS];
#pragma unroll
        for (int kh = 0; kh < 2; ++kh) {
            s16x8 aF[MW], bF[2];
#pragma unroll
            for (int mt = 0; mt < MW; ++mt) aF[mt] = *(const s16x8*)&ls[kh * 4096 + ((gA + mt) * 64 + lane) * 8];
#pragma unroll
            for (int nt = 0; nt < 2; ++nt) bF[nt] = *(const s16x8*)&ls[8192 + kh * BKH + ((gB + nt) * 64 + lane) * 8];
#pragma unroll
            for (int mt = 0; mt < MW; ++mt)
#pragma unroll
                for (int nt = 0; nt < 2; ++nt)
                    acc[mt][nt] = __builtin_amdgcn_mfma_f32_16x16x32_bf16(aF[mt], bF[nt], acc[mt][nt], 0, 0, 0);
        }
        __builtin_amdgcn_s_barrier();   // readers of buf kb&1 done -> reusable
    }

    // ---- epilogue ----
    const int ml = lane & 15, quad = lane >> 4;
    const int wm = (TN == 128) ? ((wave >> 2) * 64) : ((wave >> 1) * 32);
    const int wn = (TN == 128) ? ((wave & 3) * 32) : ((wave & 1) * 32);
    u16* Cb16 = (u16*)(seg ? p.C2 : p.C1);
    float* Cb32 = (float*)(seg ? p.C2 : p.C1);
    const int haveC = (seg ? p.C2 : p.C1) != nullptr;
    const int obf = seg ? p.obf2 : p.obf1;
    const int ldc = seg ? p.ldc2 : p.ldc1;
    if (haveC) { if (obf) Cb16 += z * p.sC; else Cb32 += z * p.sC; }
    u16* CTb = seg ? p.CT2 : p.CT1;
    if (CTb) CTb += z * p.sCT;
    const u16* CiT = (const u16*)(seg ? p.Ci2 : p.Ci1);
    const float* Ci32 = (const float*)(seg ? p.Ci2 : p.Ci1);
    const int cm = seg ? p.cm2 : p.cm1;
    const int ldci = seg ? p.ldci2 : p.ldci1;
    {
        const long sCi = seg ? p.sCi2 : p.sCi1;
        if (cm) CiT += z * sCi; else Ci32 += z * sCi;
    }
    const float pal = (EPI == 4) ? p.prelu[p.pidx] : 0.0f;
    const float* scp = (EPI == 8) ? (seg ? p.sc2 : p.sc1) : nullptr;
    const int* eselm = (EPI == 8) ? (seg ? p.selm2 : p.selm1) : nullptr;
    const int* eseli2 = (EPI == 8) ? (seg ? p.seli2 : p.seli1) : nullptr;

    const bool useEp = haveC && (obf == 1);
    u16* Lds = (u16*)LS;
    const int bb = m0 >> 9, ss = m0 & 511;
    // coop coords for [TN][128] Ci/CT tiles
    const int cd  = (TN == 128) ? (tid >> 2) : (tid >> 3);
    const int cso = (TN == 128) ? ((tid & 3) * 32) : ((tid & 7) * 16);
    constexpr int CJ = (TN == 128) ? 4 : 2;

    // ---- phase Ci: coalesced Cin ----
    float cinAll[MW * 2][4];
    if (EPI == 3 || EPI == 4 || EPI == 7 || EPI == 8) {
        if (cm) {
            __syncthreads();   // K-loop LDS done
            const u16* srcc = CiT + (long)bb * SD_ + (long)(n0 + cd) * 512 + ss + cso;
            u16* dstc = &Lds[cd * 136 + cso];
#pragma unroll
            for (int j = 0; j < CJ; ++j) *(s16x8*)&dstc[j * 8] = *(const s16x8*)&srcc[j * 8];
            __syncthreads();
#pragma unroll
            for (int mt = 0; mt < MW; ++mt)
#pragma unroll
                for (int nt = 0; nt < 2; ++nt) {
                    const ushort4 c4 = *(const ushort4*)&Lds[(wn + nt * 16 + ml) * 136 + wm + mt * 16 + quad * 4];
                    cinAll[mt * 2 + nt][0] = bf2f(c4.x); cinAll[mt * 2 + nt][1] = bf2f(c4.y);
                    cinAll[mt * 2 + nt][2] = bf2f(c4.z); cinAll[mt * 2 + nt][3] = bf2f(c4.w);
                }
        } else if (EPI == 7 && TN == 128) {
            // fp32 Cin coalesced via LDS float[128][68], two 64-col halves
            float* Lf = (float*)LS;
            const int lr = tid >> 2, lc = (tid & 3) * 16;
#pragma unroll
            for (int h = 0; h < 2; ++h) {
                __syncthreads();
                const float* src = Ci32 + (long)(m0 + lr) * ldci + n0 + h * 64 + lc;
                float* dst = &Lf[lr * 68 + lc];
#pragma unroll
                for (int j = 0; j < 4; ++j) *(float4*)&dst[j * 4] = *(const float4*)&src[j * 4];
                __syncthreads();
#pragma unroll
                for (int mt = 0; mt < MW; ++mt)
#pragma unroll
                    for (int nt = 0; nt < 2; ++nt) {
                        const int colL = wn + nt * 16 + ml;
                        if ((colL >> 6) == h) {
#pragma unroll
                            for (int r = 0; r < 4; ++r)
                                cinAll[mt * 2 + nt][r] = Lf[(wm + mt * 16 + quad * 4 + r) * 68 + (colL & 63)];
                        }
                    }
            }
        } else {
#pragma unroll
            for (int mt = 0; mt < MW; ++mt)
#pragma unroll
                for (int nt = 0; nt < 2; ++nt) {
                    const int col = n0 + wn + nt * 16 + ml;
                    const int rowb = m0 + wm + mt * 16 + quad * 4;
#pragma unroll
                    for (int r = 0; r < 4; ++r) cinAll[mt * 2 + nt][r] = Ci32[(long)(rowb + r) * ldci + col];
                }
        }
    }

    // ---- compute ----
    u16 pkAll[MW * 2][4];
#pragma unroll
    for (int mt = 0; mt < MW; ++mt) {
#pragma unroll
        for (int nt = 0; nt < 2; ++nt) {
            const int col = n0 + wn + nt * 16 + ml;
            const int rowb = m0 + wm + mt * 16 + quad * 4;
#pragma unroll
            for (int r = 0; r < 4; ++r) {
                const int row = rowb + r;
                float x = acc[mt][nt][r];
                if (EPI == 1) x += p.bias[col];
                else if (EPI == 3) x += cinAll[mt * 2 + nt][r];
                else if (EPI == 4) {
                    x = (x + p.bS * p.bias[col] + cinAll[mt * 2 + nt][r]) * p.invden[z * p.M + row];
                    x = (x >= 0.0f) ? x : pal * x;
                }
                else if (EPI == 6) x = sigmoidf_(x + p.bias[col]);
                else if (EPI == 7) x += p.bias[col] + cinAll[mt * 2 + nt][r];
                else if (EPI == 8) {
                    float av;
                    if (eselm[row]) av = bf2f(p.DG[(long)(((row >> 9) << 3) + eseli2[row]) * 512 + col]);
                    else av = bf2f(Ab[(long)row * lda + col]);
                    x = sigmoidf_(x + cinAll[mt * 2 + nt][r]) * scp[row] * av;
                }
                if (haveC && obf == 0) Cb32[(long)row * ldc + col] = x;
                pkAll[mt * 2 + nt][r] = f2bf(x);
            }
        }
    }

    // ---- phase CT: transposed store via LDS, coalesced drain ----
    if (CTb) {
        __syncthreads();
#pragma unroll
        for (int mt = 0; mt < MW; ++mt)
#pragma unroll
            for (int nt = 0; nt < 2; ++nt)
                *(ushort4*)&Lds[(wn + nt * 16 + ml) * 136 + wm + mt * 16 + quad * 4] =
                    *(const ushort4*)&pkAll[mt * 2 + nt][0];
        __syncthreads();
        u16* dstt = CTb + (long)bb * SD_ + (long)(n0 + cd) * 512 + ss + cso;
#pragma unroll
        for (int j = 0; j < CJ; ++j) *(s16x8*)&dstt[j * 8] = *(const s16x8*)&Lds[cd * 136 + cso + j * 8];
    }

    // ---- phase C: bf16 normal store via LDS, coalesced drain ----
    if (useEp) {
        constexpr int LDC2 = (TN == 128) ? 136 : 72;
        __syncthreads();
#pragma unroll
        for (int mt = 0; mt < MW; ++mt)
#pragma unroll
            for (int nt = 0; nt < 2; ++nt)
#pragma unroll
                for (int r = 0; r < 4; ++r)
                    Lds[(wm + mt * 16 + quad * 4 + r) * LDC2 + wn + nt * 16 + ml] = pkAll[mt * 2 + nt][r];
        __syncthreads();
        const int cd2 = tid >> 2, cso2 = (tid & 3) * (TN == 128 ? 32 : 16);
#pragma unroll
        for (int j = 0; j < CJ; ++j) {
            const s16x8 v = *(const s16x8*)&Lds[cd2 * LDC2 + cso2 + j * 8];
            *(s16x8*)&Cb16[(long)(m0 + cd2) * ldc + n0 + cso2 + j * 8] = v;
        }
    }
}

// --------------------------- pre-pass conversions ---------------------------
// fused bf16 convert for frontrel/backrel (adj now converted inside e0_k)
__global__ __launch_bounds__(256)
void cvt2_k(const float* __restrict__ s0, const float* __restrict__ s1,
            u16* __restrict__ d0, u16* __restrict__ d1)
{
    const int g = blockIdx.x >> 12;
    const float* s = g ? s1 : s0;
    u16* d = g ? d1 : d0;
    const long i = ((long)(blockIdx.x & 4095) * 256 + threadIdx.x) * 4;
    const float4 v = *(const float4*)&s[i];
    ushort4 h = { f2bf(v.x), f2bf(v.y), f2bf(v.z), f2bf(v.w) };
    *(ushort4*)&d[i] = h;
}

__device__ __forceinline__ void trcvt_body(u16 (*t)[72], const float* s, u16* dstT, u16* dstN,
                                           const int R, const int C, const int r0, const int c0,
                                           const int tid)
{
    const int lr = tid >> 2, lc4 = (tid & 3) * 16;
#pragma unroll
    for (int j = 0; j < 4; ++j) {
        const float4 v = *(const float4*)&s[(long)(r0 + lr) * C + c0 + lc4 + j * 4];
        ushort4 h = { f2bf(v.x), f2bf(v.y), f2bf(v.z), f2bf(v.w) };
        *(ushort4*)&t[lr][lc4 + j * 4] = h;
        if (dstN) *(ushort4*)&dstN[(long)(r0 + lr) * C + c0 + lc4 + j * 4] = h;
    }
    __syncthreads();
    const int lcol = tid >> 2, rc = (tid & 3) * 16;
#pragma unroll
    for (int j = 0; j < 2; ++j) {
        s16x8 v;
#pragma unroll
        for (int q = 0; q < 8; ++q) v[q] = (short)t[rc + j * 8 + q][lcol];
        *(s16x8*)&dstT[(long)(c0 + lcol) * R + r0 + rc + j * 8] = v;
    }
}

// generic single transpose+cvt (WoutT)
__global__ __launch_bounds__(256)
void trcvt_k(const float* __restrict__ src, u16* __restrict__ dstT, u16* __restrict__ dstN,
             const int R, const int C)
{
    __shared__ u16 t[64][72];
    trcvt_body(t, src, dstT, dstN, R, C, blockIdx.y * 64, blockIdx.x * 64, threadIdx.x);
}

// fused z=32: z<16 -> (gcn: T+N), z>=16 -> (rel: T+N); all 512x512 batch SD_
__global__ __launch_bounds__(256)
void trcvt2_k(const float* __restrict__ sA, u16* __restrict__ tA, u16* __restrict__ nA,
              const float* __restrict__ sB, u16* __restrict__ tB, u16* __restrict__ nB)
{
    __shared__ u16 t[64][72];
    const int zz = blockIdx.z, z = zz & 15;
    const long off = (long)z * SD_;
    const float* s = ((zz < 16) ? sA : sB) + off;
    u16* dT = ((zz < 16) ? tA : tB) + off;
    u16* dN = ((zz < 16) ? nA : nB) + off;
    trcvt_body(t, s, dT, dN, 512, 512, blockIdx.y * 64, blockIdx.x * 64, threadIdx.x);
}

// fused z=6 weight transposes: 0->WmgT1, 1->WmgT2, 2->WdgT, 3..5->WlT[z-3]
__global__ __launch_bounds__(256)
void trcvtW_k(const float* __restrict__ Wmg, const float* __restrict__ Wdg,
              const float* __restrict__ Wl, u16* __restrict__ T1, u16* __restrict__ T2,
              u16* __restrict__ Td, u16* __restrict__ Tl)
{
    __shared__ u16 t[64][72];
    const int z = blockIdx.z;
    const float* src;
    u16* dst;
    if (z == 0)      { src = Wmg;            dst = T1; }
    else if (z == 1) { src = Wmg + SD_;      dst = T2; }
    else if (z == 2) { src = Wdg;            dst = Td; }
    else             { src = Wl + (long)(z - 3) * SD_;  dst = Tl + (long)(z - 3) * SD_; }
    trcvt_body(t, src, dst, nullptr, 512, 512, blockIdx.y * 64, blockIdx.x * 64, threadIdx.x);
}

// ---------------------------------------------------------------------------
// e0: per-(b,s)-row reductions + adj->bf16 conversion (fused: adj is read
// here anyway; removes a full adj pass from the cvt kernel)
__global__ __launch_bounds__(256)
void e0_k(const float* __restrict__ adj, const float* __restrict__ depmap,
          const float* __restrict__ domain_id, const float* __restrict__ redomain_id,
          float* __restrict__ invden, float* __restrict__ fa, int* __restrict__ dcol,
          int* __restrict__ dm, int* __restrict__ dsel, int* __restrict__ rm, int* __restrict__ rsel,
          u16* __restrict__ adjb)
{
    const int bs = blockIdx.x;
    const int t = threadIdx.x;
    const float* arow = adj + (long)bs * 512;
    const float* drow = depmap + (long)bs * 512;
    __shared__ float red[256];
    __shared__ int scol;
    if (t == 0) scol = 0;
    const float a0 = arow[t], a1 = arow[t + 256];
    const float p0 = drow[t], p1 = drow[t + 256];
    adjb[(long)bs * 512 + t] = f2bf(a0);
    adjb[(long)bs * 512 + t + 256] = f2bf(a1);
    if (p0 > 0.5f) scol = t;
    if (p1 > 0.5f) scol = t + 256;
    red[t] = a0 + a1;
    __syncthreads();
    for (int off = 128; off > 0; off >>= 1) { if (t < off) red[t] += red[t + off]; __syncthreads(); }
    if (t == 0) invden[bs] = 1.0f / (red[0] + 1.0f);
    __syncthreads();
    red[t] = a0 * p0 + a1 * p1;
    __syncthreads();
    for (int off = 128; off > 0; off >>= 1) { if (t < off) red[t] += red[t + off]; __syncthreads(); }
    if (t == 0) {
        fa[bs] = red[0];
        dcol[bs] = scol;
        const float* q = domain_id + (long)bs * 8;
        float s = 0.f; int sel = 0;
        for (int k = 0; k < 8; ++k) { float v = q[k]; s += v; if (v > 0.5f) sel = k; }
        dm[bs] = (s > 0.5f) ? 1 : 0; dsel[bs] = sel;
        const float* r = redomain_id + (long)bs * 8;
        s = 0.f; sel = 0;
        for (int k = 0; k < 8; ++k) { float v = r[k]; s += v; if (v > 0.5f) sel = k; }
        rm[bs] = (s > 0.5f) ? 1 : 0; rsel[bs] = sel;
    }
}

__global__ void e0b_k(const float* __restrict__ adj, const int* __restrict__ dcol, float* __restrict__ ba)
{
    const int bs = blockIdx.x * 256 + threadIdx.x;
    const int b = bs >> 9, s = bs & 511;
    ba[bs] = adj[((long)b * 512 + dcol[bs]) * 512 + s];
}

// pool pass1 (chunked masked max) + OxR^T = (OUT .* rel)^T, all bf16
__global__ __launch_bounds__(256)
void pool1_k(const u16* __restrict__ OUT, const int ldO, const int* __restrict__ domain,
             const u16* __restrict__ relb, u16* __restrict__ cm, u16* __restrict__ OxRT)
{
    const int b = blockIdx.x >> 4, c = blockIdx.x & 15;
    const int s0 = c * 32, tid = threadIdx.x;
    __shared__ int dom[256];
    dom[tid] = domain[((long)(b * 512 + s0 + (tid >> 3))) * 8 + (tid & 7)];
    __syncthreads();
    const int d0 = tid * 2;
    float mxa[8], mxb[8];
#pragma unroll
    for (int k = 0; k < 8; ++k) { mxa[k] = -10000.0f; mxb[k] = -10000.0f; }
    s16x8 pA[4], pB[4];
#pragma unroll
    for (int s = 0; s < 32; ++s) {
        const int row = b * 512 + s0 + s;
        const unsigned uv = *(const unsigned*)&OUT[(long)row * ldO + d0];
        const unsigned rv = *(const unsigned*)&relb[(long)row * 512 + d0];
        const float vx = bf2f((u16)(uv & 0xffff)), vy = bf2f((u16)(uv >> 16));
        const float rx = bf2f((u16)(rv & 0xffff)), ry = bf2f((u16)(rv >> 16));
        pA[s >> 3][s & 7] = (short)f2bf(vx * rx);
        pB[s >> 3][s & 7] = (short)f2bf(vy * ry);
        const int* ds = &dom[s * 8];
#pragma unroll
        for (int k = 0; k < 8; ++k) {
            mxa[k] = fmaxf(mxa[k], ds[k] ? -10000.0f : vx);
            mxb[k] = fmaxf(mxb[k], ds[k] ? -10000.0f : vy);
        }
    }
#pragma unroll
    for (int j = 0; j < 4; ++j) *(s16x8*)&OxRT[((long)b * 512 + d0) * 512 + s0 + j * 8] = pA[j];
#pragma unroll
    for (int j = 0; j < 4; ++j) *(s16x8*)&OxRT[((long)b * 512 + d0 + 1) * 512 + s0 + j * 8] = pB[j];
#pragma unroll
    for (int k = 0; k < 8; ++k) {
        ushort2 h = { f2bf(mxa[k]), f2bf(mxb[k]) };
        *(ushort2*)&cm[((long)((b * 16 + c) * 8 + k)) * 512 + d0] = h;
    }
}

__global__ void pool2_k(const u16* __restrict__ cm, u16* __restrict__ pooled)
{
    const int q = blockIdx.x * 256 + threadIdx.x;      // 65536
    const int b = q >> 12, k = (q >> 9) & 7, d = q & 511;
    float m = -1e30f;
    for (int c = 0; c < 16; ++c)
        m = fmaxf(m, bf2f(cm[((long)((b * 16 + c) * 8 + k)) * 512 + d]));
    pooled[((long)(b * 8 + k)) * 512 + d] = f2bf(m);
}

extern "C" void kernel_launch(void* const* d_in, const int* in_sizes, int n_in,
                              void* d_out, int out_size, void* d_ws, size_t ws_size,
                              hipStream_t stream)
{
    const float* adj         = (const float*)d_in[0];
    const int*   domain      = (const int*)d_in[1];
    const float* domain_id   = (const float*)d_in[2];
    const float* redomain_id = (const float*)d_in[3];
    const float* frontrel    = (const float*)d_in[4];
    const float* backrel     = (const float*)d_in[5];
    const float* depmap      = (const float*)d_in[6];
    const float* rel         = (const float*)d_in[7];
    const float* gcn         = (const float*)d_in[8];
    const float* W_layers    = (const float*)d_in[10];
    const float* b_layers    = (const float*)d_in[11];
    const float* prelu_a     = (const float*)d_in[12];
    const float* W_dg        = (const float*)d_in[13];
    const float* b_dg        = (const float*)d_in[14];
    const float* W_mg        = (const float*)d_in[15];
    const float* b_mg        = (const float*)d_in[16];
    const float* W_out       = (const float*)d_in[17];
    const float* b_out       = (const float*)d_in[18];
    float* out = (float*)d_out;

    char* w = (char*)d_ws;
    auto alloc = [&](size_t bytes) { void* p = (void*)w; w += (bytes + 255) & ~(size_t)255; return p; };
    const size_t Bb = (size_t)BSD_ * 2;
    u16* OUTS_bf = (u16*)alloc((size_t)8192 * 1536 * 2);
    u16* OUTT    = (u16*)alloc(Bb);   // layer output transposed [b][d][s]
    u16* gcnT    = (u16*)alloc(Bb);
    u16* RB_bf   = (u16*)alloc(Bb);   // normal [b][s][d]
    u16* XBT     = (u16*)alloc(Bb);   // [b][d][s]
    u16* XFT     = (u16*)alloc(Bb);   // [b][d][s]
    u16* OxRT    = (u16*)alloc(Bb);
    u16* DLT     = (u16*)alloc(Bb);   // [b][d][s]
    u16* AXO_bf  = (u16*)alloc(Bb);   // normal
    u16* BBT     = (u16*)alloc(Bb);   // [b][d][s]
    u16* FBT     = (u16*)alloc(Bb);
    u16* rel_bf  = (u16*)alloc(Bb);
    u16* relT_bf = (u16*)alloc(Bb);
    u16* adj_bf  = (u16*)alloc(Bb);
    u16* gcn_bf  = (u16*)alloc(Bb);
    u16* frel_bf = (u16*)alloc(Bb);
    u16* brel_bf = (u16*)alloc(Bb);
    u16* WmgT1 = (u16*)alloc((size_t)SD_ * 2);
    u16* WmgT2 = (u16*)alloc((size_t)SD_ * 2);
    u16* WdgT  = (u16*)alloc((size_t)SD_ * 2);
    u16* WlT   = (u16*)alloc((size_t)3 * SD_ * 2);
    u16* WoutT = (u16*)alloc((size_t)512 * 1536 * 2);
    u16* cm     = (u16*)alloc((size_t)16 * 16 * 8 * 512 * 2);
    u16* pooled = (u16*)alloc((size_t)16 * 8 * 512 * 2);
    u16* DGb    = (u16*)alloc((size_t)16 * 8 * 512 * 2);   // bf16 domain gates
    float* invden = (float*)alloc(8192 * 4);
    float* fa     = (float*)alloc(8192 * 4);
    float* ba     = (float*)alloc(8192 * 4);
    int* dcol = (int*)alloc(8192 * 4);
    int* dm   = (int*)alloc(8192 * 4);
    int* dsel = (int*)alloc(8192 * 4);
    int* rm   = (int*)alloc(8192 * 4);
    int* rsel = (int*)alloc(8192 * 4);

    // ---- pre-pass (6 launches, was 10) ----
    e0_k<<<8192, 256, 0, stream>>>(adj, depmap, domain_id, redomain_id, invden, fa, dcol, dm, dsel, rm, rsel, adj_bf);
    e0b_k<<<32, 256, 0, stream>>>(adj, dcol, ba);
    cvt2_k<<<8192, 256, 0, stream>>>(frontrel, backrel, frel_bf, brel_bf);
    trcvt2_k<<<dim3(8, 8, 32), 256, 0, stream>>>(gcn, gcnT, gcn_bf, rel, relT_bf, rel_bf);
    trcvtW_k<<<dim3(8, 8, 6), 256, 0, stream>>>(W_mg, W_dg, W_layers, WmgT1, WmgT2, WdgT, WlT);
    trcvt_k<<<dim3(8, 24, 1), 256, 0, stream>>>(W_out, WoutT, nullptr, 1536, 512);

    const dim3 blk(512);

    // BBT/FBT = ({back,front}rel @ WmgT2 + b_mg)^T  (z=2 merged, 512 blocks, TN=128)
    {
        GP p{};
        p.A1 = brel_bf; p.A2 = frel_bf; p.lda1 = p.lda2 = 512; p.sA = 0;
        p.B1 = p.B2 = WmgT2; p.ldb1 = p.ldb2 = 512; p.sB = 0;
        p.CT1 = BBT; p.CT2 = FBT; p.sCT = 0;
        p.bias = b_mg; p.M = 8192; p.K = 512; p.zs = 1; p.swzX = 2; p.swzY = 6;
        gemm3<1, 0, 128><<<dim3(4, 64, 2), blk, 0, stream>>>(p);
    }

    for (int l = 0; l < 3; ++l) {
        const u16* OUTp  = (l == 0) ? gcn_bf : (OUTS_bf + (l - 1) * 512);
        const u16* OUTTp = (l == 0) ? gcnT : OUTT;
        const int ldO = (l == 0) ? 512 : 1536;

        // RB = rel @ outputs (B = OUT^T)  (TN=64 -> 512 blocks = 2/CU)
        {
            GP p{};
            p.A1 = rel_bf; p.lda1 = 512; p.sA = SD_;
            p.B1 = OUTTp; p.ldb1 = 512; p.sB = SD_;
            p.C1 = RB_bf; p.obf1 = 1; p.ldc1 = 512; p.sC = SD_;
            p.M = 512; p.K = 512; p.zs = 16; p.swzX = 3; p.swzY = 2;
            gemm3<0, 0, 64><<<dim3(8, 4, 16), blk, 0, stream>>>(p);
        }
        pool1_k<<<256, 256, 0, stream>>>(OUTp, ldO, domain, rel_bf, cm, OxRT);
        pool2_k<<<256, 256, 0, stream>>>(cm, pooled);
        // DG = sigm(pooled @ WdgT + b_dg)  (bf16 out, TN=64 -> 8 blocks)
        {
            GP p{};
            p.A1 = pooled; p.lda1 = 512; p.B1 = WdgT; p.ldb1 = 512;
            p.C1 = DGb; p.obf1 = 1; p.ldc1 = 512;
            p.bias = b_dg; p.M = 128; p.K = 512; p.zs = 1; p.swzX = -1;
            gemm3<6, 0, 64><<<dim3(8, 1, 1), blk, 0, stream>>>(p);
        }
        // gates (z=2): z0: XBT = (ba*sigm(RBeff@W1+BB)*RBeff)^T ; z1: XFT = (...)^T  (TN=128)
        {
            GP p{};
            p.A1 = RB_bf; p.lda1 = 512; p.A2 = OUTp; p.lda2 = ldO; p.sA = 0;
            p.selm1 = rm; p.seli1 = rsel; p.selm2 = dm; p.seli2 = dsel; p.DG = DGb;
            p.B1 = p.B2 = WmgT1; p.ldb1 = p.ldb2 = 512; p.sB = 0;
            p.Ci1 = BBT; p.Ci2 = FBT; p.cm1 = p.cm2 = 1; p.ldci1 = p.ldci2 = 512; p.sCi1 = p.sCi2 = 0;
            p.CT1 = XBT; p.CT2 = XFT; p.sCT = 0;
            p.sc1 = ba; p.sc2 = fa; p.M = 8192; p.K = 512; p.zs = 1; p.swzX = 2; p.swzY = 6;
            gemm3<8, 1, 128><<<dim3(4, 64, 2), blk, 0, stream>>>(p);
        }
        // merged z=32: z<16: DLT = (relT @ XF + XB)^T ; z>=16: AXO = adj @ OxR + OUT  (TN=128)
        {
            GP p{};
            p.A1 = relT_bf; p.lda1 = 512; p.A2 = adj_bf; p.lda2 = 512; p.sA = SD_;
            p.B1 = XFT; p.ldb1 = 512;
            p.B2 = OxRT; p.ldb2 = 512; p.sB = SD_;
            p.Ci1 = XBT; p.cm1 = 1; p.ldci1 = 512; p.sCi1 = SD_;
            p.Ci2 = OUTTp; p.cm2 = 1; p.ldci2 = 512; p.sCi2 = SD_;
            p.CT1 = DLT; p.sCT = SD_;
            p.C2 = AXO_bf; p.obf2 = 1; p.ldc2 = 512; p.sC = SD_;
            p.M = 512; p.K = 512; p.zs = 16; p.swzX = 2; p.swzY = 2;
            gemm3<3, 0, 128><<<dim3(4, 4, 32), blk, 0, stream>>>(p);
        }
        // outs[l] = PReLU((AXO@W + 2b + DL)*invden)  (TN=64 -> 512 blocks = 2/CU)
        {
            GP p{};
            p.A1 = AXO_bf; p.lda1 = 512; p.sA = SD_;
            p.B1 = WlT + (long)l * SD_; p.ldb1 = 512; p.sB = 0;
            p.Ci1 = DLT; p.cm1 = 1; p.ldci1 = 512; p.sCi1 = SD_;
            p.C1 = OUTS_bf + l * 512; p.obf1 = 1; p.ldc1 = 1536; p.sC = (long)512 * 1536;
            p.CT1 = OUTT; p.sCT = SD_;
            p.bias = b_layers + l * 512; p.bS = 2.0f;
            p.invden = invden; p.prelu = prelu_a; p.pidx = l;
            p.M = 512; p.K = 512; p.zs = 16; p.swzX = 3; p.swzY = 2;
            gemm3<4, 0, 64><<<dim3(8, 4, 16), blk, 0, stream>>>(p);
        }
    }

    // out = OUTS @ W_out + b_out + gcn   (K=1536, fp32 direct, TN=128)
    {
        GP p{};
        p.A1 = OUTS_bf; p.lda1 = 1536; p.sA = 0;
        p.B1 = WoutT; p.ldb1 = 1536; p.sB = 0;
        p.Ci1 = gcn; p.cm1 = 0; p.ldci1 = 512; p.sCi1 = 0;
        p.C1 = out; p.obf1 = 0; p.ldc1 = 512; p.sC = 0;
        p.bias = b_out; p.M = 8192; p.K = 1536; p.zs = 1; p.swzX = 2; p.swzY = 6;
        gemm3<7, 0, 128><<<dim3(4, 64, 1), blk, 0, stream>>>(p);
    }
}